// Round 1
// baseline (1896.998 us; speedup 1.0000x reference)
//
#include <hip/hip_runtime.h>
#include <stdint.h>

// ---------------------------------------------------------------------------
// AttentionBlock (MLA-style) on gfx950. Round 4: flash_k rewritten as
// zero-LDS swapped-operand flash attention:
//   - S^T = mfma(K,Q): softmax row m lives on lane (m=ln) -> 2 shuffles
//   - P redistributed across quads with 16 __shfl (no Ps LDS)
//   - PV = mfma(V^T, P^T): output cols m=ln -> lane-local rescale + epilogue
//   - K/V fragments read directly from global (L1/L2), no barriers
// Q is pre-scaled by SCALE*log2(e) in the projection epilogue.
// ---------------------------------------------------------------------------

typedef unsigned short u16;
typedef __bf16 bf16x8 __attribute__((ext_vector_type(8)));
typedef unsigned short u16x8 __attribute__((ext_vector_type(8)));
typedef unsigned short u16x4 __attribute__((ext_vector_type(4)));
typedef float f32x4 __attribute__((ext_vector_type(4)));

#define LOG2E 1.4426950408889634f
#define SCALE_F 0.07216878364870323f   // 1/sqrt(128+64)

__device__ __forceinline__ f32x4 mfma16(bf16x8 a, bf16x8 b, f32x4 c) {
  return __builtin_amdgcn_mfma_f32_16x16x32_bf16(a, b, c, 0, 0, 0);
}

__device__ __forceinline__ u16 f2bf(float f) {
  union { float f; unsigned u; } x; x.f = f;
  unsigned r = x.u + 0x7fffu + ((x.u >> 16) & 1u);  // RNE
  return (u16)(r >> 16);
}
__device__ __forceinline__ float bf2f(u16 v) {
  union { unsigned u; float f; } x; x.u = ((unsigned)v) << 16;
  return x.f;
}

// async global->LDS, 16 bytes per lane. LDS side must be contiguous in lane
// order (wave-uniform base + lane*16) — caller guarantees.
__device__ __forceinline__ void gload_lds16(const u16* g, u16* l) {
  __builtin_amdgcn_global_load_lds(
      (const __attribute__((address_space(1))) unsigned int*)g,
      (__attribute__((address_space(3))) unsigned int*)l, 16, 0, 0);
}

// ---------------------------------------------------------------------------
// RMSNorm: one 256-thread block per row of 2048 fp32. Output bf16.
// ---------------------------------------------------------------------------
__global__ __launch_bounds__(256) void rmsnorm_k(const float* __restrict__ x,
                                                 const float* __restrict__ g,
                                                 u16* __restrict__ out) {
  const int row = blockIdx.x;
  const int t = threadIdx.x;
  const float* xr = x + (size_t)row * 2048;
  float4 a = ((const float4*)xr)[t * 2];
  float4 b = ((const float4*)xr)[t * 2 + 1];
  float ss = a.x*a.x + a.y*a.y + a.z*a.z + a.w*a.w
           + b.x*b.x + b.y*b.y + b.z*b.z + b.w*b.w;
  #pragma unroll
  for (int off = 32; off; off >>= 1) ss += __shfl_xor(ss, off, 64);
  __shared__ float w4[4];
  if ((t & 63) == 0) w4[t >> 6] = ss;
  __syncthreads();
  ss = w4[0] + w4[1] + w4[2] + w4[3];
  const float n = rsqrtf(ss * (1.0f / 2048.0f) + 1e-6f);
  const float* gr = g + t * 8;
  u16x8 o;
  o[0] = f2bf(a.x * n * gr[0]); o[1] = f2bf(a.y * n * gr[1]);
  o[2] = f2bf(a.z * n * gr[2]); o[3] = f2bf(a.w * n * gr[3]);
  o[4] = f2bf(b.x * n * gr[4]); o[5] = f2bf(b.y * n * gr[5]);
  o[6] = f2bf(b.z * n * gr[6]); o[7] = f2bf(b.w * n * gr[7]);
  *(u16x8*)&out[(size_t)row * 2048 + t * 8] = o;
}

// ---------------------------------------------------------------------------
// Transpose-convert fp32 (R x C slab, row stride ldin) -> bf16 (C x R).
// ---------------------------------------------------------------------------
__global__ __launch_bounds__(256) void conv_t(const float* __restrict__ in,
                                              u16* __restrict__ out,
                                              int R, int C, int ldin) {
  __shared__ float tile[64][65];
  const int r0 = blockIdx.y * 64, c0 = blockIdx.x * 64;
  const int tr = threadIdx.x >> 6, tc = threadIdx.x & 63;
  #pragma unroll
  for (int i = 0; i < 16; ++i) {
    int rr = tr * 16 + i;
    tile[rr][tc] = in[(size_t)(r0 + rr) * ldin + c0 + tc];
  }
  __syncthreads();
  #pragma unroll
  for (int i = 0; i < 16; ++i) {
    int rr = tr * 16 + i;
    out[(size_t)(c0 + rr) * R + r0 + tc] = f2bf(tile[tc][rr]);
  }
}

// bf16 (R x C) -> bf16 (C x R), batched over blockIdx.z (stride R*C).
__global__ __launch_bounds__(256) void transpose_bf16(const u16* __restrict__ in,
                                                      u16* __restrict__ out,
                                                      int R, int C) {
  __shared__ u16 tile[64][65];
  const size_t zoff = (size_t)blockIdx.z * R * C;
  const u16* inz = in + zoff;
  u16* outz = out + zoff;
  const int r0 = blockIdx.y * 64, c0 = blockIdx.x * 64;
  const int tr = threadIdx.x >> 6, tc = threadIdx.x & 63;
  #pragma unroll
  for (int i = 0; i < 16; ++i) {
    int rr = tr * 16 + i;
    tile[rr][tc] = inz[(size_t)(r0 + rr) * C + c0 + tc];
  }
  __syncthreads();
  #pragma unroll
  for (int i = 0; i < 16; ++i) {
    int rr = tr * 16 + i;
    outz[(size_t)(c0 + rr) * R + r0 + tc] = tile[tc][rr];
  }
}

// ---------------------------------------------------------------------------
// RoPE in-place on cols [128,192) of a (B*NH, 2048, 192) bf16 buffer.
// ---------------------------------------------------------------------------
__global__ __launch_bounds__(256) void rope_k(u16* __restrict__ buf) {
  const int idx = blockIdx.x * 256 + threadIdx.x;
  const int i = idx & 31;
  const int pos = (idx >> 5) & 2047;
  const int bh = idx >> 16;            // 0..31
  u16* p = buf + ((size_t)(bh * 2048 + pos)) * 192 + 128 + 2 * i;
  const float inv = exp2f(-(float)(2 * i) * (19.931568569324174f / 64.0f));
  const float f = (float)pos * inv;
  const float c = cosf(f), s = sinf(f);
  const float x1 = bf2f(p[0]), x2 = bf2f(p[1]);
  p[0] = f2bf(x1 * c - x2 * s);
  p[1] = f2bf(x2 * c + x1 * s);
}

// ---------------------------------------------------------------------------
// bf16 GEMM, m97 structure: C(MxN) = A(MxK,rm) * Bt(NxK,rm)^T.
// 256 thr, 128x128 tile, BK=32, global_load_lds width=16 staging into
// unpadded 128x32 LDS tiles. Epilogues as before; EPI 1/2 (Q paths) now
// pre-scale by SCALE*log2(e) so flash_k can use exp2 directly.
// ---------------------------------------------------------------------------
template <int EPI>
__global__ __launch_bounds__(256) void gemm_bt(const u16* __restrict__ A,
                                               const u16* __restrict__ Bt,
                                               int N, int K,
                                               void* __restrict__ outp,
                                               const void* __restrict__ auxp) {
  __shared__ __attribute__((aligned(16))) u16 As[128 * 32];
  __shared__ __attribute__((aligned(16))) u16 Bs[128 * 32];
  const int t = threadIdx.x;
  const int wv = t >> 6, quad = (t >> 4) & 3, ln = t & 15;
  const int lane = t & 63;
  const int bm0 = blockIdx.y * 128, bn0 = blockIdx.x * 128;
  const int wm = (wv >> 1) * 64, wn = (wv & 1) * 64;

  f32x4 acc[4][4] = {};

  // staging coords: one instruction stages 16 rows (64 lanes x 16B).
  const int r_in = lane >> 2;          // 0..15
  const int c_in = (lane & 3) * 8;     // 0,8,16,24

  for (int kk = 0; kk < K; kk += 32) {
    #pragma unroll
    for (int i = 0; i < 2; ++i) {
      const int row = (i * 4 + wv) * 16 + r_in;
      gload_lds16(&A[(size_t)(bm0 + row) * K + kk + c_in], &As[row * 32 + c_in]);
      gload_lds16(&Bt[(size_t)(bn0 + row) * K + kk + c_in], &Bs[row * 32 + c_in]);
    }
    __syncthreads();
    bf16x8 af[4], bfr[4];
    #pragma unroll
    for (int mt = 0; mt < 4; ++mt)
      af[mt] = *(const bf16x8*)&As[(wm + mt * 16 + ln) * 32 + quad * 8];
    #pragma unroll
    for (int nt = 0; nt < 4; ++nt)
      bfr[nt] = *(const bf16x8*)&Bs[(wn + nt * 16 + ln) * 32 + quad * 8];
    #pragma unroll
    for (int mt = 0; mt < 4; ++mt)
      #pragma unroll
      for (int nt = 0; nt < 4; ++nt)
        acc[mt][nt] = mfma16(af[mt], bfr[nt], acc[mt][nt]);
    __syncthreads();
  }

  // epilogue: C row = bm0+wm+mt*16+quad*4+r, col = bn0+wn+nt*16+ln
  #pragma unroll
  for (int mt = 0; mt < 4; ++mt) {
    #pragma unroll
    for (int r = 0; r < 4; ++r) {
      const int gm = bm0 + wm + mt * 16 + quad * 4 + r;
      #pragma unroll
      for (int nt = 0; nt < 4; ++nt) {
        const int gn = bn0 + wn + nt * 16 + ln;
        float v = acc[mt][nt][r];
        if constexpr (EPI == 0) {
          ((u16*)outp)[(size_t)gm * N + gn] = f2bf(v);
        } else if constexpr (EPI >= 1 && EPI <= 4) {
          if constexpr (EPI == 1 || EPI == 2) v *= SCALE_F * LOG2E;
          const int bb = gm >> 11, mm = gm & 2047;
          int h, d, off;
          if constexpr (EPI == 1 || EPI == 3) { h = gn >> 7; d = gn & 127; off = 0; }
          else                                { h = gn >> 6; d = gn & 63; off = 128; }
          ((u16*)outp)[((size_t)((bb * 16 + h) * 2048 + mm)) * 192 + off + d] = f2bf(v);
        } else if constexpr (EPI == 5) {
          const int bb = gm >> 11, mm = gm & 2047;
          const int h = gn >> 7, d = gn & 127;
          ((u16*)outp)[((size_t)((bb * 16 + h) * 2048 + mm)) * 128 + d] = f2bf(v);
        } else if constexpr (EPI == 6) {
          ((float*)outp)[(size_t)gm * N + gn] =
              v + ((const float*)auxp)[(size_t)gm * N + gn];
        } else if constexpr (EPI == 7) {
          const float g = bf2f(((const u16*)auxp)[(size_t)gm * N + gn]);
          const float s = g / (1.0f + __expf(-g));
          ((u16*)outp)[(size_t)gm * N + gn] = f2bf(s * v);
        }
      }
    }
  }
}

// ---------------------------------------------------------------------------
// Flash attention, zero-LDS swapped-operand form.
// Q,K:(B*NH, 2048, 192) bf16 (Q pre-scaled by SCALE*log2e, tails rope'd).
// VT:(B*NH, 128, 2048) bf16. O:(B, 2048, NH*128) bf16.
// 256 thr / 4 independent waves; wave owns 16 Q rows (m = wv*16 + ln).
//
// QK^T as mfma(K, Q): sf[nt][r] = score(m=ln, n=nt*16+quad*4+r).
// Softmax is lane-local in m; reductions are shfl_xor(16) + shfl_xor(32).
// P redistributed across quads (16 shfl) into the PV B-fragment layout:
//   pa[kt] word w  <-  pk[2kt+(quad>>1)][w&1]  from lane ((quad&1)*2+(w>>1))*16+ln
// PV as mfma(V^T, P^T): of[dt] holds out[m=ln][d=dt*16+quad*4+r] -> rescale,
// final 1/l and the O store are all lane-local.
// ---------------------------------------------------------------------------
__global__ __launch_bounds__(256, 4) void flash_k(const u16* __restrict__ Q,
                                                  const u16* __restrict__ K,
                                                  const u16* __restrict__ VT,
                                                  u16* __restrict__ O) {
  const int t = threadIdx.x;
  const int wv = t >> 6, quad = (t >> 4) & 3, ln = t & 15;
  const int b = blockIdx.z, h = blockIdx.y;
  const int m0 = blockIdx.x * 64;
  const size_t qbase = ((size_t)(b * 16 + h)) * 2048;

  const u16* kp = K + qbase * 192;
  const u16* vp = VT + ((size_t)(b * 16 + h)) * 128 * 2048;

  bf16x8 qf[6];
  {
    const u16* qp = Q + (qbase + m0 + wv * 16 + ln) * 192 + quad * 8;
    #pragma unroll
    for (int ks = 0; ks < 6; ++ks) qf[ks] = *(const bf16x8*)&qp[ks * 32];
  }

  float m_i = -1e30f, l_i = 0.0f;
  f32x4 of[8] = {};

  for (int j = 0; j < 32; ++j) {
    // S^T tile: sf[nt][r] = score(m = ln, n = nt*16 + quad*4 + r)
    f32x4 sf[4];
    #pragma unroll
    for (int nt = 0; nt < 4; ++nt) {
      f32x4 s = {0.f, 0.f, 0.f, 0.f};
      const u16* kr = kp + (size_t)(j * 64 + nt * 16 + ln) * 192 + quad * 8;
      #pragma unroll
      for (int ks = 0; ks < 6; ++ks) {
        bf16x8 kb = *(const bf16x8*)&kr[ks * 32];
        s = mfma16(kb, qf[ks], s);
      }
      sf[nt] = s;
    }

    // online softmax over n, lane-local in m (scores already in log2 units)
    float mx = sf[0][0];
    #pragma unroll
    for (int nt = 0; nt < 4; ++nt)
      #pragma unroll
      for (int r = 0; r < 4; ++r) mx = fmaxf(mx, sf[nt][r]);
    mx = fmaxf(mx, __shfl_xor(mx, 16, 64));
    mx = fmaxf(mx, __shfl_xor(mx, 32, 64));
    const float mn = fmaxf(m_i, mx);
    const float alpha = exp2f(m_i - mn);
    m_i = mn;
    float rs = 0.0f;
    #pragma unroll
    for (int nt = 0; nt < 4; ++nt)
      #pragma unroll
      for (int r = 0; r < 4; ++r) {
        const float p = exp2f(sf[nt][r] - mn);
        sf[nt][r] = p;
        rs += p;
      }
    rs += __shfl_xor(rs, 16, 64);
    rs += __shfl_xor(rs, 32, 64);
    l_i = l_i * alpha + rs;

    // pack P rows to bf16 pairs: pk[nt][pp] = (P[m][nt*16+quad*4+2pp],+1)
    unsigned pk[4][2];
    #pragma unroll
    for (int nt = 0; nt < 4; ++nt) {
      pk[nt][0] = (unsigned)f2bf(sf[nt][0]) | ((unsigned)f2bf(sf[nt][1]) << 16);
      pk[nt][1] = (unsigned)f2bf(sf[nt][2]) | ((unsigned)f2bf(sf[nt][3]) << 16);
    }
    // cross-quad redistribute into PV fragment: lane needs
    // P[m=ln][n = kt*32 + quad*8 + j], j=0..7 (4 dwords per kt)
    unsigned paw[2][4];
    #pragma unroll
    for (int kt = 0; kt < 2; ++kt)
      #pragma unroll
      for (int w = 0; w < 4; ++w) {
        const int src = ((quad & 1) * 2 + (w >> 1)) * 16 + ln;
        const int lo = __shfl((int)pk[2 * kt][w & 1], src, 64);
        const int hi = __shfl((int)pk[2 * kt + 1][w & 1], src, 64);
        paw[kt][w] = (unsigned)((quad & 2) ? hi : lo);
      }

    // rescale accumulator (all elements belong to m = ln)
    #pragma unroll
    for (int dt = 0; dt < 8; ++dt)
      #pragma unroll
      for (int r = 0; r < 4; ++r) of[dt][r] *= alpha;

    // PV: of[dt][r] = out[m=ln][d = dt*16 + quad*4 + r]
    #pragma unroll
    for (int kt = 0; kt < 2; ++kt) {
      union { unsigned u[4]; bf16x8 b; } pa;
      pa.u[0] = paw[kt][0]; pa.u[1] = paw[kt][1];
      pa.u[2] = paw[kt][2]; pa.u[3] = paw[kt][3];
      #pragma unroll
      for (int dt = 0; dt < 8; ++dt) {
        const u16* vr = vp + (size_t)(dt * 16 + ln) * 2048 +
                        j * 64 + kt * 32 + quad * 8;
        bf16x8 vb = *(const bf16x8*)vr;
        of[dt] = mfma16(vb, pa.b, of[dt]);
      }
    }
  }

  const float inv_l = 1.0f / l_i;
  #pragma unroll
  for (int dt = 0; dt < 8; ++dt) {
    u16x4 o4;
    #pragma unroll
    for (int r = 0; r < 4; ++r) o4[r] = f2bf(of[dt][r] * inv_l);
    *(u16x4*)&O[((size_t)(b * 2048 + m0 + wv * 16 + ln)) * 2048 +
                h * 128 + dt * 16 + quad * 4] = o4;
  }
}

// ---------------------------------------------------------------------------
// Launch. Workspace layout (MiB offsets), phase-aliased, peak 104 MiB.
// ---------------------------------------------------------------------------
extern "C" void kernel_launch(void* const* d_in, const int* in_sizes, int n_in,
                              void* d_out, int out_size, void* d_ws, size_t ws_size,
                              hipStream_t stream) {
  const float* query     = (const float*)d_in[0];
  const float* key_value = (const float*)d_in[1];
  const float* g_q       = (const float*)d_in[2];
  const float* g_kv      = (const float*)d_in[3];
  const float* g_ffn     = (const float*)d_in[4];
  const float* w_qc      = (const float*)d_in[5];
  const float* w_kc      = (const float*)d_in[6];
  const float* w_qr      = (const float*)d_in[7];
  const float* w_kr      = (const float*)d_in[8];
  const float* w_v       = (const float*)d_in[9];
  const float* w_o       = (const float*)d_in[10];
  const float* w_gate    = (const float*)d_in[11];
  const float* w_up      = (const float*)d_in[12];
  const float* w_down    = (const float*)d_in[13];

  char* ws = (char*)d_ws;
  const size_t MiB = 1048576;
  u16*   qn   = (u16*)(ws + 0 * MiB);
  u16*   kvn  = (u16*)(ws + 16 * MiB);
  u16*   Qb   = (u16*)(ws + 32 * MiB);
  u16*   Kb   = (u16*)(ws + 56 * MiB);
  u16*   Vb   = (u16*)(ws + 80 * MiB);
  u16*   wt   = (u16*)(ws + 96 * MiB);   // 8 MiB slab (proj weights)
  u16*   VT   = (u16*)(ws + 0 * MiB);    // over qn (dead)
  u16*   attn = (u16*)(ws + 16 * MiB);   // over kvn (dead)
  float* x    = (float*)(ws + 64 * MiB); // over Kb-tail+Vb (dead)
  u16*   xn   = (u16*)(ws + 0 * MiB);    // over VT (dead)
  u16*   ghalf= (u16*)(ws + 16 * MiB);   // over attn+Qb-head (dead), 32 MiB
  u16*   wtf  = (u16*)(ws + 48 * MiB);   // over Qb-tail+Kb-head (dead), 16 MiB

  const dim3 blk(256);

  // input norms
  rmsnorm_k<<<4096, blk, 0, stream>>>(query, g_q, qn);
  rmsnorm_k<<<4096, blk, 0, stream>>>(key_value, g_kv, kvn);

  // Q projections (qn dead after these)
  conv_t<<<dim3(32, 32), blk, 0, stream>>>(w_qc, wt, 2048, 2048, 2048);
  gemm_bt<1><<<dim3(16, 32), blk, 0, stream>>>(qn, wt, 2048, 2048, Qb, nullptr);
  conv_t<<<dim3(16, 32), blk, 0, stream>>>(w_qr, wt, 2048, 1024, 1024);
  gemm_bt<2><<<dim3(8, 32), blk, 0, stream>>>(qn, wt, 1024, 2048, Qb, nullptr);
  // K projections
  conv_t<<<dim3(32, 32), blk, 0, stream>>>(w_kc, wt, 2048, 2048, 2048);
  gemm_bt<3><<<dim3(16, 32), blk, 0, stream>>>(kvn, wt, 2048, 2048, Kb, nullptr);
  conv_t<<<dim3(16, 32), blk, 0, stream>>>(w_kr, wt, 2048, 1024, 1024);
  gemm_bt<4><<<dim3(8, 32), blk, 0, stream>>>(kvn, wt, 1024, 2048, Kb, nullptr);
  // V projection (kvn dead after)
  conv_t<<<dim3(32, 32), blk, 0, stream>>>(w_v, wt, 2048, 2048, 2048);
  gemm_bt<5><<<dim3(16, 32), blk, 0, stream>>>(kvn, wt, 2048, 2048, Vb, nullptr);

  // RoPE tails
  rope_k<<<8192, blk, 0, stream>>>(Qb);
  rope_k<<<8192, blk, 0, stream>>>(Kb);

  // V -> V^T per head (Vb -> VT; VT aliases dead qn)
  transpose_bf16<<<dim3(2, 32, 32), blk, 0, stream>>>(Vb, VT, 2048, 128);

  // flash attention -> attn (aliases dead kvn)
  flash_k<<<dim3(32, 16, 2), blk, 0, stream>>>(Qb, Kb, VT, attn);

  // out projection + residual -> x fp32 (aliases dead Kb-tail/Vb)
  conv_t<<<dim3(32, 32), blk, 0, stream>>>(w_o, wt, 2048, 2048, 2048);
  gemm_bt<6><<<dim3(16, 32), blk, 0, stream>>>(attn, wt, 2048, 2048, x, query);

  // FFN: rmsnorm then two N=4096 halves with split-K accumulation into d_out
  rmsnorm_k<<<4096, blk, 0, stream>>>(x, g_ffn, xn);
  for (int h = 0; h < 2; ++h) {
    const int n0 = h * 4096;
    conv_t<<<dim3(64, 32), blk, 0, stream>>>(w_gate + n0, wtf, 2048, 4096, 8192);
    gemm_bt<0><<<dim3(32, 32), blk, 0, stream>>>(xn, wtf, 4096, 2048, ghalf, nullptr);
    conv_t<<<dim3(64, 32), blk, 0, stream>>>(w_up + n0, wtf, 2048, 4096, 8192);
    gemm_bt<7><<<dim3(32, 32), blk, 0, stream>>>(xn, wtf, 4096, 2048, ghalf, ghalf);
    conv_t<<<dim3(32, 64), blk, 0, stream>>>(w_down + (size_t)n0 * 2048, wtf,
                                             4096, 2048, 2048);
    gemm_bt<6><<<dim3(16, 32), blk, 0, stream>>>(ghalf, wtf, 2048, 4096,
                                                 (float*)d_out,
                                                 h == 0 ? (const void*)x
                                                        : (const void*)d_out);
  }
}

// Round 2
// 1464.261 us; speedup vs baseline: 1.2955x; 1.2955x over previous
//
#include <hip/hip_runtime.h>
#include <stdint.h>

// ---------------------------------------------------------------------------
// AttentionBlock (MLA-style) on gfx950. Round 5: flash_k = swapped-operand
// flash (verified R4 math) + LDS staging restored with 2x register reuse:
//   - 32 m-rows per wave (groups A/B): each K/V LDS fragment feeds 2 MFMAs
//   - K double-buffered, V single-buffered (64 KiB LDS total)
//   - global_load_lds w=16 staging, inverse-swizzled source + swizzled reads
//     (XOR (row&7)<<4) -> 2-way bank access on all fragment reads
//   - K(j+1) prefetch issued before compute(j); V(j+1) staged after PV barrier
//   - lane-local softmax (2 shuffles), 16-shfl P redistribute per group,
//     defer-max rescale (skip O rescale when max growth <= 11 log2-units)
// ---------------------------------------------------------------------------

typedef unsigned short u16;
typedef __bf16 bf16x8 __attribute__((ext_vector_type(8)));
typedef unsigned short u16x8 __attribute__((ext_vector_type(8)));
typedef unsigned short u16x4 __attribute__((ext_vector_type(4)));
typedef float f32x4 __attribute__((ext_vector_type(4)));

#define LOG2E 1.4426950408889634f
#define SCALE_F 0.07216878364870323f   // 1/sqrt(128+64)

__device__ __forceinline__ f32x4 mfma16(bf16x8 a, bf16x8 b, f32x4 c) {
  return __builtin_amdgcn_mfma_f32_16x16x32_bf16(a, b, c, 0, 0, 0);
}

__device__ __forceinline__ u16 f2bf(float f) {
  union { float f; unsigned u; } x; x.f = f;
  unsigned r = x.u + 0x7fffu + ((x.u >> 16) & 1u);  // RNE
  return (u16)(r >> 16);
}
__device__ __forceinline__ float bf2f(u16 v) {
  union { unsigned u; float f; } x; x.u = ((unsigned)v) << 16;
  return x.f;
}

// async global->LDS, 16 bytes per lane. LDS dest is wave-uniform base +
// lane*16 (linear); caller passes per-lane pointer equal to that.
__device__ __forceinline__ void gload_lds16(const u16* g, u16* l) {
  __builtin_amdgcn_global_load_lds(
      (const __attribute__((address_space(1))) unsigned int*)g,
      (__attribute__((address_space(3))) unsigned int*)l, 16, 0, 0);
}

// ---------------------------------------------------------------------------
// RMSNorm: one 256-thread block per row of 2048 fp32. Output bf16.
// ---------------------------------------------------------------------------
__global__ __launch_bounds__(256) void rmsnorm_k(const float* __restrict__ x,
                                                 const float* __restrict__ g,
                                                 u16* __restrict__ out) {
  const int row = blockIdx.x;
  const int t = threadIdx.x;
  const float* xr = x + (size_t)row * 2048;
  float4 a = ((const float4*)xr)[t * 2];
  float4 b = ((const float4*)xr)[t * 2 + 1];
  float ss = a.x*a.x + a.y*a.y + a.z*a.z + a.w*a.w
           + b.x*b.x + b.y*b.y + b.z*b.z + b.w*b.w;
  #pragma unroll
  for (int off = 32; off; off >>= 1) ss += __shfl_xor(ss, off, 64);
  __shared__ float w4[4];
  if ((t & 63) == 0) w4[t >> 6] = ss;
  __syncthreads();
  ss = w4[0] + w4[1] + w4[2] + w4[3];
  const float n = rsqrtf(ss * (1.0f / 2048.0f) + 1e-6f);
  const float* gr = g + t * 8;
  u16x8 o;
  o[0] = f2bf(a.x * n * gr[0]); o[1] = f2bf(a.y * n * gr[1]);
  o[2] = f2bf(a.z * n * gr[2]); o[3] = f2bf(a.w * n * gr[3]);
  o[4] = f2bf(b.x * n * gr[4]); o[5] = f2bf(b.y * n * gr[5]);
  o[6] = f2bf(b.z * n * gr[6]); o[7] = f2bf(b.w * n * gr[7]);
  *(u16x8*)&out[(size_t)row * 2048 + t * 8] = o;
}

// ---------------------------------------------------------------------------
// Transpose-convert fp32 (R x C slab, row stride ldin) -> bf16 (C x R).
// ---------------------------------------------------------------------------
__global__ __launch_bounds__(256) void conv_t(const float* __restrict__ in,
                                              u16* __restrict__ out,
                                              int R, int C, int ldin) {
  __shared__ float tile[64][65];
  const int r0 = blockIdx.y * 64, c0 = blockIdx.x * 64;
  const int tr = threadIdx.x >> 6, tc = threadIdx.x & 63;
  #pragma unroll
  for (int i = 0; i < 16; ++i) {
    int rr = tr * 16 + i;
    tile[rr][tc] = in[(size_t)(r0 + rr) * ldin + c0 + tc];
  }
  __syncthreads();
  #pragma unroll
  for (int i = 0; i < 16; ++i) {
    int rr = tr * 16 + i;
    out[(size_t)(c0 + rr) * R + r0 + tc] = f2bf(tile[tc][rr]);
  }
}

// bf16 (R x C) -> bf16 (C x R), batched over blockIdx.z (stride R*C).
__global__ __launch_bounds__(256) void transpose_bf16(const u16* __restrict__ in,
                                                      u16* __restrict__ out,
                                                      int R, int C) {
  __shared__ u16 tile[64][65];
  const size_t zoff = (size_t)blockIdx.z * R * C;
  const u16* inz = in + zoff;
  u16* outz = out + zoff;
  const int r0 = blockIdx.y * 64, c0 = blockIdx.x * 64;
  const int tr = threadIdx.x >> 6, tc = threadIdx.x & 63;
  #pragma unroll
  for (int i = 0; i < 16; ++i) {
    int rr = tr * 16 + i;
    tile[rr][tc] = inz[(size_t)(r0 + rr) * C + c0 + tc];
  }
  __syncthreads();
  #pragma unroll
  for (int i = 0; i < 16; ++i) {
    int rr = tr * 16 + i;
    outz[(size_t)(c0 + rr) * R + r0 + tc] = tile[tc][rr];
  }
}

// ---------------------------------------------------------------------------
// RoPE in-place on cols [128,192) of a (B*NH, 2048, 192) bf16 buffer.
// ---------------------------------------------------------------------------
__global__ __launch_bounds__(256) void rope_k(u16* __restrict__ buf) {
  const int idx = blockIdx.x * 256 + threadIdx.x;
  const int i = idx & 31;
  const int pos = (idx >> 5) & 2047;
  const int bh = idx >> 16;            // 0..31
  u16* p = buf + ((size_t)(bh * 2048 + pos)) * 192 + 128 + 2 * i;
  const float inv = exp2f(-(float)(2 * i) * (19.931568569324174f / 64.0f));
  const float f = (float)pos * inv;
  const float c = cosf(f), s = sinf(f);
  const float x1 = bf2f(p[0]), x2 = bf2f(p[1]);
  p[0] = f2bf(x1 * c - x2 * s);
  p[1] = f2bf(x2 * c + x1 * s);
}

// ---------------------------------------------------------------------------
// bf16 GEMM, m97 structure: C(MxN) = A(MxK,rm) * Bt(NxK,rm)^T.
// EPI 1/2 (Q paths) pre-scale by SCALE*log2(e) so flash_k uses exp2 directly.
// ---------------------------------------------------------------------------
template <int EPI>
__global__ __launch_bounds__(256) void gemm_bt(const u16* __restrict__ A,
                                               const u16* __restrict__ Bt,
                                               int N, int K,
                                               void* __restrict__ outp,
                                               const void* __restrict__ auxp) {
  __shared__ __attribute__((aligned(16))) u16 As[128 * 32];
  __shared__ __attribute__((aligned(16))) u16 Bs[128 * 32];
  const int t = threadIdx.x;
  const int wv = t >> 6, quad = (t >> 4) & 3, ln = t & 15;
  const int lane = t & 63;
  const int bm0 = blockIdx.y * 128, bn0 = blockIdx.x * 128;
  const int wm = (wv >> 1) * 64, wn = (wv & 1) * 64;

  f32x4 acc[4][4] = {};

  const int r_in = lane >> 2;          // 0..15
  const int c_in = (lane & 3) * 8;     // 0,8,16,24

  for (int kk = 0; kk < K; kk += 32) {
    #pragma unroll
    for (int i = 0; i < 2; ++i) {
      const int row = (i * 4 + wv) * 16 + r_in;
      gload_lds16(&A[(size_t)(bm0 + row) * K + kk + c_in], &As[row * 32 + c_in]);
      gload_lds16(&Bt[(size_t)(bn0 + row) * K + kk + c_in], &Bs[row * 32 + c_in]);
    }
    __syncthreads();
    bf16x8 af[4], bfr[4];
    #pragma unroll
    for (int mt = 0; mt < 4; ++mt)
      af[mt] = *(const bf16x8*)&As[(wm + mt * 16 + ln) * 32 + quad * 8];
    #pragma unroll
    for (int nt = 0; nt < 4; ++nt)
      bfr[nt] = *(const bf16x8*)&Bs[(wn + nt * 16 + ln) * 32 + quad * 8];
    #pragma unroll
    for (int mt = 0; mt < 4; ++mt)
      #pragma unroll
      for (int nt = 0; nt < 4; ++nt)
        acc[mt][nt] = mfma16(af[mt], bfr[nt], acc[mt][nt]);
    __syncthreads();
  }

  #pragma unroll
  for (int mt = 0; mt < 4; ++mt) {
    #pragma unroll
    for (int r = 0; r < 4; ++r) {
      const int gm = bm0 + wm + mt * 16 + quad * 4 + r;
      #pragma unroll
      for (int nt = 0; nt < 4; ++nt) {
        const int gn = bn0 + wn + nt * 16 + ln;
        float v = acc[mt][nt][r];
        if constexpr (EPI == 0) {
          ((u16*)outp)[(size_t)gm * N + gn] = f2bf(v);
        } else if constexpr (EPI >= 1 && EPI <= 4) {
          if constexpr (EPI == 1 || EPI == 2) v *= SCALE_F * LOG2E;
          const int bb = gm >> 11, mm = gm & 2047;
          int h, d, off;
          if constexpr (EPI == 1 || EPI == 3) { h = gn >> 7; d = gn & 127; off = 0; }
          else                                { h = gn >> 6; d = gn & 63; off = 128; }
          ((u16*)outp)[((size_t)((bb * 16 + h) * 2048 + mm)) * 192 + off + d] = f2bf(v);
        } else if constexpr (EPI == 5) {
          const int bb = gm >> 11, mm = gm & 2047;
          const int h = gn >> 7, d = gn & 127;
          ((u16*)outp)[((size_t)((bb * 16 + h) * 2048 + mm)) * 128 + d] = f2bf(v);
        } else if constexpr (EPI == 6) {
          ((float*)outp)[(size_t)gm * N + gn] =
              v + ((const float*)auxp)[(size_t)gm * N + gn];
        } else if constexpr (EPI == 7) {
          const float g = bf2f(((const u16*)auxp)[(size_t)gm * N + gn]);
          const float s = g / (1.0f + __expf(-g));
          ((u16*)outp)[(size_t)gm * N + gn] = f2bf(s * v);
        }
      }
    }
  }
}

// ---------------------------------------------------------------------------
// Flash attention, swapped-operand, LDS-staged, 32 m-rows per wave.
// Q,K:(B*NH, 2048, 192) bf16 (Q pre-scaled by SCALE*log2e, tails rope'd).
// VT:(B*NH, 128, 2048) bf16. O:(B, 2048, NH*128) bf16.
// 256 thr / 4 waves; block owns 128 m rows; wave owns rows
//   A: m0 + wv*16 + ln,  B: m0 + 64 + wv*16 + ln.
// K tile (64x192) double-buffered, V^T tile (128x64) single-buffered; both
// staged via global_load_lds w=16 with inverse-swizzled source (XOR
// (row&7)<<4 on the byte column) so swizzled ds_reads are 2-way conflict.
// ---------------------------------------------------------------------------
__global__ __launch_bounds__(256, 2) void flash_k(const u16* __restrict__ Q,
                                                  const u16* __restrict__ K,
                                                  const u16* __restrict__ VT,
                                                  u16* __restrict__ O) {
  __shared__ __attribute__((aligned(16))) u16 Ks[2][64 * 192];
  __shared__ __attribute__((aligned(16))) u16 Vs[128 * 64];

  const int t = threadIdx.x;
  const int wv = t >> 6, quad = (t >> 4) & 3, ln = t & 15;
  const int lane = t & 63;
  const int b = blockIdx.z, h = blockIdx.y;
  const int m0 = blockIdx.x * 128;
  const size_t qbase = ((size_t)(b * 16 + h)) * 2048;
  const u16* kg = K + qbase * 192;
  const u16* vg = VT + ((size_t)(b * 16 + h)) * 128 * 2048;

  // Per-thread staging coordinates (constants across j).
  int krow[6], kscol[6];               // K: row in tile, swizzled byte col
  #pragma unroll
  for (int i = 0; i < 6; ++i) {
    const int o = (wv * 6 + i) * 1024 + lane * 16;
    const int r = o / 384;
    const int c = o - r * 384;
    krow[i] = r;
    kscol[i] = c ^ ((r & 7) << 4);
  }
  int vrow[4], vscol[4];               // V: row (=d), swizzled byte col
  #pragma unroll
  for (int i = 0; i < 4; ++i) {
    const int o = (wv * 4 + i) * 1024 + lane * 16;
    const int r = o >> 7;
    vrow[i] = r;
    vscol[i] = (o & 127) ^ ((r & 7) << 4);
  }

  // Q fragments, two row groups.
  bf16x8 qfA[6], qfB[6];
  {
    const u16* qpA = Q + (qbase + m0 + wv * 16 + ln) * 192 + quad * 8;
    const u16* qpB = qpA + 64 * 192;
    #pragma unroll
    for (int ks = 0; ks < 6; ++ks) {
      qfA[ks] = *(const bf16x8*)&qpA[ks * 32];
      qfB[ks] = *(const bf16x8*)&qpB[ks * 32];
    }
  }

  float mA = -1e30f, lA = 0.0f, mB = -1e30f, lB = 0.0f;
  f32x4 ofA[8] = {}, ofB[8] = {};

  // prologue: stage tile 0 (K into buf 0, V)
  #pragma unroll
  for (int i = 0; i < 6; ++i)
    gload_lds16(kg + (size_t)krow[i] * 192 + (kscol[i] >> 1),
                &Ks[0][(wv * 6 + i) * 512 + lane * 8]);
  #pragma unroll
  for (int i = 0; i < 4; ++i)
    gload_lds16(vg + (size_t)vrow[i] * 2048 + (vscol[i] >> 1),
                &Vs[(wv * 4 + i) * 512 + lane * 8]);
  __syncthreads();

  int cur = 0;
  for (int j = 0; j < 32; ++j) {
    // prefetch next K tile into the other buffer
    if (j < 31) {
      #pragma unroll
      for (int i = 0; i < 6; ++i)
        gload_lds16(kg + (size_t)((j + 1) * 64 + krow[i]) * 192 + (kscol[i] >> 1),
                    &Ks[cur ^ 1][(wv * 6 + i) * 512 + lane * 8]);
    }

    // S^T tiles for both row groups: s[nt][r] = score(m, n = nt*16+quad*4+r)
    f32x4 sA[4], sB[4];
    #pragma unroll
    for (int nt = 0; nt < 4; ++nt) {
      f32x4 za = {0.f, 0.f, 0.f, 0.f}, zb = {0.f, 0.f, 0.f, 0.f};
      const int row = nt * 16 + ln;
      const u16* kr = &Ks[cur][row * 192];
      const int sw = (row & 7) << 4;
      #pragma unroll
      for (int ks = 0; ks < 6; ++ks) {
        bf16x8 kb = *(const bf16x8*)&kr[((ks * 64 + quad * 16) ^ sw) >> 1];
        za = mfma16(kb, qfA[ks], za);
        zb = mfma16(kb, qfB[ks], zb);
      }
      sA[nt] = za; sB[nt] = zb;
    }

    // online softmax (lane-local in m; scores already in log2 units)
    float mxA = sA[0][0], mxB = sB[0][0];
    #pragma unroll
    for (int nt = 0; nt < 4; ++nt)
      #pragma unroll
      for (int r = 0; r < 4; ++r) {
        mxA = fmaxf(mxA, sA[nt][r]);
        mxB = fmaxf(mxB, sB[nt][r]);
      }
    mxA = fmaxf(mxA, __shfl_xor(mxA, 16, 64));
    mxA = fmaxf(mxA, __shfl_xor(mxA, 32, 64));
    mxB = fmaxf(mxB, __shfl_xor(mxB, 16, 64));
    mxB = fmaxf(mxB, __shfl_xor(mxB, 32, 64));

    // defer-max: only rescale when the running max grew materially
    if (__any((mxA > mA + 11.0f) || (mxB > mB + 11.0f))) {
      const float mnA = fmaxf(mA, mxA), mnB = fmaxf(mB, mxB);
      const float aA = exp2f(mA - mnA), aB = exp2f(mB - mnB);
      mA = mnA; mB = mnB;
      lA *= aA; lB *= aB;
      #pragma unroll
      for (int dt = 0; dt < 8; ++dt)
        #pragma unroll
        for (int r = 0; r < 4; ++r) {
          ofA[dt][r] *= aA;
          ofB[dt][r] *= aB;
        }
    }

    float rsA = 0.0f, rsB = 0.0f;
    #pragma unroll
    for (int nt = 0; nt < 4; ++nt)
      #pragma unroll
      for (int r = 0; r < 4; ++r) {
        const float pa = exp2f(sA[nt][r] - mA);
        const float pb = exp2f(sB[nt][r] - mB);
        sA[nt][r] = pa; sB[nt][r] = pb;
        rsA += pa; rsB += pb;
      }
    rsA += __shfl_xor(rsA, 16, 64);
    rsA += __shfl_xor(rsA, 32, 64);
    rsB += __shfl_xor(rsB, 16, 64);
    rsB += __shfl_xor(rsB, 32, 64);
    lA += rsA; lB += rsB;

    // pack P rows to bf16 pairs
    unsigned pkA[4][2], pkB[4][2];
    #pragma unroll
    for (int nt = 0; nt < 4; ++nt) {
      pkA[nt][0] = (unsigned)f2bf(sA[nt][0]) | ((unsigned)f2bf(sA[nt][1]) << 16);
      pkA[nt][1] = (unsigned)f2bf(sA[nt][2]) | ((unsigned)f2bf(sA[nt][3]) << 16);
      pkB[nt][0] = (unsigned)f2bf(sB[nt][0]) | ((unsigned)f2bf(sB[nt][1]) << 16);
      pkB[nt][1] = (unsigned)f2bf(sB[nt][2]) | ((unsigned)f2bf(sB[nt][3]) << 16);
    }
    // cross-quad redistribute into PV B-fragment layout (verified R4 mapping)
    unsigned pawA[2][4], pawB[2][4];
    #pragma unroll
    for (int kt = 0; kt < 2; ++kt)
      #pragma unroll
      for (int w = 0; w < 4; ++w) {
        const int src = ((quad & 1) * 2 + (w >> 1)) * 16 + ln;
        const int loA = __shfl((int)pkA[2 * kt][w & 1], src, 64);
        const int hiA = __shfl((int)pkA[2 * kt + 1][w & 1], src, 64);
        pawA[kt][w] = (unsigned)((quad & 2) ? hiA : loA);
        const int loB = __shfl((int)pkB[2 * kt][w & 1], src, 64);
        const int hiB = __shfl((int)pkB[2 * kt + 1][w & 1], src, 64);
        pawB[kt][w] = (unsigned)((quad & 2) ? hiB : loB);
      }

    __syncthreads();   // V(j) staged (vmcnt drained) before PV reads

    // PV: of[dt][r] = out[m][d = dt*16 + quad*4 + r]
    #pragma unroll
    for (int kt = 0; kt < 2; ++kt) {
      union { unsigned u[4]; bf16x8 b; } paA, paB;
      #pragma unroll
      for (int w = 0; w < 4; ++w) { paA.u[w] = pawA[kt][w]; paB.u[w] = pawB[kt][w]; }
      #pragma unroll
      for (int dt = 0; dt < 8; ++dt) {
        const int row = dt * 16 + ln;
        const int sw = (row & 7) << 4;
        bf16x8 vb = *(const bf16x8*)&Vs[row * 64 +
                                        (((kt * 64 + quad * 16) ^ sw) >> 1)];
        ofA[dt] = mfma16(vb, paA.b, ofA[dt]);
        ofB[dt] = mfma16(vb, paB.b, ofB[dt]);
      }
    }

    __syncthreads();   // all waves done reading Vs -> safe to overwrite

    if (j < 31) {
      #pragma unroll
      for (int i = 0; i < 4; ++i)
        gload_lds16(vg + (size_t)vrow[i] * 2048 + (j + 1) * 64 + (vscol[i] >> 1),
                    &Vs[(wv * 4 + i) * 512 + lane * 8]);
    }
    cur ^= 1;
  }

  const float invA = 1.0f / lA, invB = 1.0f / lB;
  #pragma unroll
  for (int dt = 0; dt < 8; ++dt) {
    u16x4 oa, ob;
    #pragma unroll
    for (int r = 0; r < 4; ++r) {
      oa[r] = f2bf(ofA[dt][r] * invA);
      ob[r] = f2bf(ofB[dt][r] * invB);
    }
    *(u16x4*)&O[((size_t)(b * 2048 + m0 + wv * 16 + ln)) * 2048 +
                h * 128 + dt * 16 + quad * 4] = oa;
    *(u16x4*)&O[((size_t)(b * 2048 + m0 + 64 + wv * 16 + ln)) * 2048 +
                h * 128 + dt * 16 + quad * 4] = ob;
  }
}

// ---------------------------------------------------------------------------
// Launch. Workspace layout (MiB offsets), phase-aliased, peak 104 MiB.
// ---------------------------------------------------------------------------
extern "C" void kernel_launch(void* const* d_in, const int* in_sizes, int n_in,
                              void* d_out, int out_size, void* d_ws, size_t ws_size,
                              hipStream_t stream) {
  const float* query     = (const float*)d_in[0];
  const float* key_value = (const float*)d_in[1];
  const float* g_q       = (const float*)d_in[2];
  const float* g_kv      = (const float*)d_in[3];
  const float* g_ffn     = (const float*)d_in[4];
  const float* w_qc      = (const float*)d_in[5];
  const float* w_kc      = (const float*)d_in[6];
  const float* w_qr      = (const float*)d_in[7];
  const float* w_kr      = (const float*)d_in[8];
  const float* w_v       = (const float*)d_in[9];
  const float* w_o       = (const float*)d_in[10];
  const float* w_gate    = (const float*)d_in[11];
  const float* w_up      = (const float*)d_in[12];
  const float* w_down    = (const float*)d_in[13];

  char* ws = (char*)d_ws;
  const size_t MiB = 1048576;
  u16*   qn   = (u16*)(ws + 0 * MiB);
  u16*   kvn  = (u16*)(ws + 16 * MiB);
  u16*   Qb   = (u16*)(ws + 32 * MiB);
  u16*   Kb   = (u16*)(ws + 56 * MiB);
  u16*   Vb   = (u16*)(ws + 80 * MiB);
  u16*   wt   = (u16*)(ws + 96 * MiB);   // 8 MiB slab (proj weights)
  u16*   VT   = (u16*)(ws + 0 * MiB);    // over qn (dead)
  u16*   attn = (u16*)(ws + 16 * MiB);   // over kvn (dead)
  float* x    = (float*)(ws + 64 * MiB); // over Kb-tail+Vb (dead)
  u16*   xn   = (u16*)(ws + 0 * MiB);    // over VT (dead)
  u16*   ghalf= (u16*)(ws + 16 * MiB);   // over attn+Qb-head (dead), 32 MiB
  u16*   wtf  = (u16*)(ws + 48 * MiB);   // over Qb-tail+Kb-head (dead), 16 MiB

  const dim3 blk(256);

  // input norms
  rmsnorm_k<<<4096, blk, 0, stream>>>(query, g_q, qn);
  rmsnorm_k<<<4096, blk, 0, stream>>>(key_value, g_kv, kvn);

  // Q projections (qn dead after these)
  conv_t<<<dim3(32, 32), blk, 0, stream>>>(w_qc, wt, 2048, 2048, 2048);
  gemm_bt<1><<<dim3(16, 32), blk, 0, stream>>>(qn, wt, 2048, 2048, Qb, nullptr);
  conv_t<<<dim3(16, 32), blk, 0, stream>>>(w_qr, wt, 2048, 1024, 1024);
  gemm_bt<2><<<dim3(8, 32), blk, 0, stream>>>(qn, wt, 1024, 2048, Qb, nullptr);
  // K projections
  conv_t<<<dim3(32, 32), blk, 0, stream>>>(w_kc, wt, 2048, 2048, 2048);
  gemm_bt<3><<<dim3(16, 32), blk, 0, stream>>>(kvn, wt, 2048, 2048, Kb, nullptr);
  conv_t<<<dim3(16, 32), blk, 0, stream>>>(w_kr, wt, 2048, 1024, 1024);
  gemm_bt<4><<<dim3(8, 32), blk, 0, stream>>>(kvn, wt, 1024, 2048, Kb, nullptr);
  // V projection (kvn dead after)
  conv_t<<<dim3(32, 32), blk, 0, stream>>>(w_v, wt, 2048, 2048, 2048);
  gemm_bt<5><<<dim3(16, 32), blk, 0, stream>>>(kvn, wt, 2048, 2048, Vb, nullptr);

  // RoPE tails
  rope_k<<<8192, blk, 0, stream>>>(Qb);
  rope_k<<<8192, blk, 0, stream>>>(Kb);

  // V -> V^T per head (Vb -> VT; VT aliases dead qn)
  transpose_bf16<<<dim3(2, 32, 32), blk, 0, stream>>>(Vb, VT, 2048, 128);

  // flash attention -> attn (aliases dead kvn)
  flash_k<<<dim3(16, 16, 2), blk, 0, stream>>>(Qb, Kb, VT, attn);

  // out projection + residual -> x fp32 (aliases dead Kb-tail/Vb)
  conv_t<<<dim3(32, 32), blk, 0, stream>>>(w_o, wt, 2048, 2048, 2048);
  gemm_bt<6><<<dim3(16, 32), blk, 0, stream>>>(attn, wt, 2048, 2048, x, query);

  // FFN: rmsnorm then two N=4096 halves with split-K accumulation into d_out
  rmsnorm_k<<<4096, blk, 0, stream>>>(x, g_ffn, xn);
  for (int h = 0; h < 2; ++h) {
    const int n0 = h * 4096;
    conv_t<<<dim3(64, 32), blk, 0, stream>>>(w_gate + n0, wtf, 2048, 4096, 8192);
    gemm_bt<0><<<dim3(32, 32), blk, 0, stream>>>(xn, wtf, 4096, 2048, ghalf, nullptr);
    conv_t<<<dim3(64, 32), blk, 0, stream>>>(w_up + n0, wtf, 2048, 4096, 8192);
    gemm_bt<7><<<dim3(32, 32), blk, 0, stream>>>(xn, wtf, 4096, 2048, ghalf, ghalf);
    conv_t<<<dim3(32, 64), blk, 0, stream>>>(w_down + (size_t)n0 * 2048, wtf,
                                             4096, 2048, 2048);
    gemm_bt<6><<<dim3(16, 32), blk, 0, stream>>>(ghalf, wtf, 2048, 4096,
                                                 (float*)d_out,
                                                 h == 0 ? (const void*)x
                                                        : (const void*)d_out);
  }
}

// Round 3
// 1329.985 us; speedup vs baseline: 1.4263x; 1.1010x over previous
//
#include <hip/hip_runtime.h>
#include <stdint.h>

// ---------------------------------------------------------------------------
// AttentionBlock (MLA-style) on gfx950. Round 6:
//   - gemm_bt: BK=64 (half the barriers), XOR-swizzled LDS (row&7)<<4 with
//     pre-swizzled global source (R5-flash-proven pattern) -> conflict-free
//     ds_read_b128; bijective XCD-aware block swizzle for A-panel L2 reuse.
//   - flash_k: v_cvt_pk_bf16_f32 for the P->bf16 pack (1 instr per word
//     instead of ~7 VALU of manual RNE bit-twiddle).
//   - everything else identical to R5 (passed, 1464 us).
// ---------------------------------------------------------------------------

typedef unsigned short u16;
typedef __bf16 bf16x8 __attribute__((ext_vector_type(8)));
typedef unsigned short u16x8 __attribute__((ext_vector_type(8)));
typedef unsigned short u16x4 __attribute__((ext_vector_type(4)));
typedef float f32x4 __attribute__((ext_vector_type(4)));

#define LOG2E 1.4426950408889634f
#define SCALE_F 0.07216878364870323f   // 1/sqrt(128+64)

__device__ __forceinline__ f32x4 mfma16(bf16x8 a, bf16x8 b, f32x4 c) {
  return __builtin_amdgcn_mfma_f32_16x16x32_bf16(a, b, c, 0, 0, 0);
}

__device__ __forceinline__ u16 f2bf(float f) {
  union { float f; unsigned u; } x; x.f = f;
  unsigned r = x.u + 0x7fffu + ((x.u >> 16) & 1u);  // RNE
  return (u16)(r >> 16);
}
__device__ __forceinline__ float bf2f(u16 v) {
  union { unsigned u; float f; } x; x.u = ((unsigned)v) << 16;
  return x.f;
}
// packed f32x2 -> bf16x2 (hardware RNE), gfx950
__device__ __forceinline__ unsigned cvt_pk_bf16(float lo, float hi) {
  unsigned r;
  asm("v_cvt_pk_bf16_f32 %0, %1, %2" : "=v"(r) : "v"(lo), "v"(hi));
  return r;
}

// async global->LDS, 16 bytes per lane. LDS dest is wave-uniform base +
// lane*16 (linear); caller passes per-lane pointer equal to that.
__device__ __forceinline__ void gload_lds16(const u16* g, u16* l) {
  __builtin_amdgcn_global_load_lds(
      (const __attribute__((address_space(1))) unsigned int*)g,
      (__attribute__((address_space(3))) unsigned int*)l, 16, 0, 0);
}

// ---------------------------------------------------------------------------
// RMSNorm: one 256-thread block per row of 2048 fp32. Output bf16.
// ---------------------------------------------------------------------------
__global__ __launch_bounds__(256) void rmsnorm_k(const float* __restrict__ x,
                                                 const float* __restrict__ g,
                                                 u16* __restrict__ out) {
  const int row = blockIdx.x;
  const int t = threadIdx.x;
  const float* xr = x + (size_t)row * 2048;
  float4 a = ((const float4*)xr)[t * 2];
  float4 b = ((const float4*)xr)[t * 2 + 1];
  float ss = a.x*a.x + a.y*a.y + a.z*a.z + a.w*a.w
           + b.x*b.x + b.y*b.y + b.z*b.z + b.w*b.w;
  #pragma unroll
  for (int off = 32; off; off >>= 1) ss += __shfl_xor(ss, off, 64);
  __shared__ float w4[4];
  if ((t & 63) == 0) w4[t >> 6] = ss;
  __syncthreads();
  ss = w4[0] + w4[1] + w4[2] + w4[3];
  const float n = rsqrtf(ss * (1.0f / 2048.0f) + 1e-6f);
  const float* gr = g + t * 8;
  u16x8 o;
  o[0] = f2bf(a.x * n * gr[0]); o[1] = f2bf(a.y * n * gr[1]);
  o[2] = f2bf(a.z * n * gr[2]); o[3] = f2bf(a.w * n * gr[3]);
  o[4] = f2bf(b.x * n * gr[4]); o[5] = f2bf(b.y * n * gr[5]);
  o[6] = f2bf(b.z * n * gr[6]); o[7] = f2bf(b.w * n * gr[7]);
  *(u16x8*)&out[(size_t)row * 2048 + t * 8] = o;
}

// ---------------------------------------------------------------------------
// Transpose-convert fp32 (R x C slab, row stride ldin) -> bf16 (C x R).
// ---------------------------------------------------------------------------
__global__ __launch_bounds__(256) void conv_t(const float* __restrict__ in,
                                              u16* __restrict__ out,
                                              int R, int C, int ldin) {
  __shared__ float tile[64][65];
  const int r0 = blockIdx.y * 64, c0 = blockIdx.x * 64;
  const int tr = threadIdx.x >> 6, tc = threadIdx.x & 63;
  #pragma unroll
  for (int i = 0; i < 16; ++i) {
    int rr = tr * 16 + i;
    tile[rr][tc] = in[(size_t)(r0 + rr) * ldin + c0 + tc];
  }
  __syncthreads();
  #pragma unroll
  for (int i = 0; i < 16; ++i) {
    int rr = tr * 16 + i;
    out[(size_t)(c0 + rr) * R + r0 + tc] = f2bf(tile[tc][rr]);
  }
}

// bf16 (R x C) -> bf16 (C x R), batched over blockIdx.z (stride R*C).
__global__ __launch_bounds__(256) void transpose_bf16(const u16* __restrict__ in,
                                                      u16* __restrict__ out,
                                                      int R, int C) {
  __shared__ u16 tile[64][65];
  const size_t zoff = (size_t)blockIdx.z * R * C;
  const u16* inz = in + zoff;
  u16* outz = out + zoff;
  const int r0 = blockIdx.y * 64, c0 = blockIdx.x * 64;
  const int tr = threadIdx.x >> 6, tc = threadIdx.x & 63;
  #pragma unroll
  for (int i = 0; i < 16; ++i) {
    int rr = tr * 16 + i;
    tile[rr][tc] = inz[(size_t)(r0 + rr) * C + c0 + tc];
  }
  __syncthreads();
  #pragma unroll
  for (int i = 0; i < 16; ++i) {
    int rr = tr * 16 + i;
    outz[(size_t)(c0 + rr) * R + r0 + tc] = tile[tc][rr];
  }
}

// ---------------------------------------------------------------------------
// RoPE in-place on cols [128,192) of a (B*NH, 2048, 192) bf16 buffer.
// ---------------------------------------------------------------------------
__global__ __launch_bounds__(256) void rope_k(u16* __restrict__ buf) {
  const int idx = blockIdx.x * 256 + threadIdx.x;
  const int i = idx & 31;
  const int pos = (idx >> 5) & 2047;
  const int bh = idx >> 16;            // 0..31
  u16* p = buf + ((size_t)(bh * 2048 + pos)) * 192 + 128 + 2 * i;
  const float inv = exp2f(-(float)(2 * i) * (19.931568569324174f / 64.0f));
  const float f = (float)pos * inv;
  const float c = cosf(f), s = sinf(f);
  const float x1 = bf2f(p[0]), x2 = bf2f(p[1]);
  p[0] = f2bf(x1 * c - x2 * s);
  p[1] = f2bf(x2 * c + x1 * s);
}

// ---------------------------------------------------------------------------
// bf16 GEMM: C(MxN) = A(MxK,rm) * Bt(NxK,rm)^T.
// 256 thr, 128x128 tile, BK=64, 2-barrier loop.
// LDS tiles [128][64] u16 with byte-col XOR swizzle ((row&7)<<4), staged via
// global_load_lds w=16 from pre-swizzled source (linear LDS dest).
// Bijective XCD swizzle on the block index (grid always %8==0).
// EPI 1/2 (Q paths) pre-scale by SCALE*log2(e).
// ---------------------------------------------------------------------------
template <int EPI>
__global__ __launch_bounds__(256) void gemm_bt(const u16* __restrict__ A,
                                               const u16* __restrict__ Bt,
                                               int N, int K,
                                               void* __restrict__ outp,
                                               const void* __restrict__ auxp) {
  __shared__ __attribute__((aligned(16))) u16 As[128 * 64];
  __shared__ __attribute__((aligned(16))) u16 Bs[128 * 64];
  const int t = threadIdx.x;
  const int wv = t >> 6, quad = (t >> 4) & 3, ln = t & 15;

  // XCD-aware bijective block swizzle: contiguous tile chunk per XCD.
  const int nbx = gridDim.x;
  const int lin = blockIdx.y * nbx + blockIdx.x;
  const int cpx = (nbx * gridDim.y) >> 3;
  const int swz = (lin & 7) * cpx + (lin >> 3);
  const int bm0 = (swz / nbx) * 128, bn0 = (swz % nbx) * 128;
  const int wm = (wv >> 1) * 64, wn = (wv & 1) * 64;

  f32x4 acc[4][4] = {};

  // staging coords: 4 loads per matrix per K-step; thread covers physical
  // bytes o = i*4096 + t*16 of the [128][64] tile (row = o>>7).
  int srow[4], scol[4];
  #pragma unroll
  for (int i = 0; i < 4; ++i) {
    const int row = i * 32 + (t >> 3);
    const int cB = ((t & 7) * 16) ^ ((row & 7) << 4);   // logical byte col
    srow[i] = row;
    scol[i] = cB >> 1;                                   // u16 units
  }

  for (int kk = 0; kk < K; kk += 64) {
    #pragma unroll
    for (int i = 0; i < 4; ++i) {
      gload_lds16(&A[(size_t)(bm0 + srow[i]) * K + kk + scol[i]],
                  &As[i * 2048 + t * 8]);
      gload_lds16(&Bt[(size_t)(bn0 + srow[i]) * K + kk + scol[i]],
                  &Bs[i * 2048 + t * 8]);
    }
    __syncthreads();
    #pragma unroll
    for (int ks = 0; ks < 2; ++ks) {
      bf16x8 af[4], bfr[4];
      #pragma unroll
      for (int mt = 0; mt < 4; ++mt) {
        const int row = wm + mt * 16 + ln;
        af[mt] = *(const bf16x8*)&As[row * 64 +
                   (((ks * 64 + quad * 16) ^ ((row & 7) << 4)) >> 1)];
      }
      #pragma unroll
      for (int nt = 0; nt < 4; ++nt) {
        const int row = wn + nt * 16 + ln;
        bfr[nt] = *(const bf16x8*)&Bs[row * 64 +
                   (((ks * 64 + quad * 16) ^ ((row & 7) << 4)) >> 1)];
      }
      #pragma unroll
      for (int mt = 0; mt < 4; ++mt)
        #pragma unroll
        for (int nt = 0; nt < 4; ++nt)
          acc[mt][nt] = mfma16(af[mt], bfr[nt], acc[mt][nt]);
    }
    __syncthreads();
  }

  // epilogue: C row = bm0+wm+mt*16+quad*4+r, col = bn0+wn+nt*16+ln
  #pragma unroll
  for (int mt = 0; mt < 4; ++mt) {
    #pragma unroll
    for (int r = 0; r < 4; ++r) {
      const int gm = bm0 + wm + mt * 16 + quad * 4 + r;
      #pragma unroll
      for (int nt = 0; nt < 4; ++nt) {
        const int gn = bn0 + wn + nt * 16 + ln;
        float v = acc[mt][nt][r];
        if constexpr (EPI == 0) {
          ((u16*)outp)[(size_t)gm * N + gn] = f2bf(v);
        } else if constexpr (EPI >= 1 && EPI <= 4) {
          if constexpr (EPI == 1 || EPI == 2) v *= SCALE_F * LOG2E;
          const int bb = gm >> 11, mm = gm & 2047;
          int h, d, off;
          if constexpr (EPI == 1 || EPI == 3) { h = gn >> 7; d = gn & 127; off = 0; }
          else                                { h = gn >> 6; d = gn & 63; off = 128; }
          ((u16*)outp)[((size_t)((bb * 16 + h) * 2048 + mm)) * 192 + off + d] = f2bf(v);
        } else if constexpr (EPI == 5) {
          const int bb = gm >> 11, mm = gm & 2047;
          const int h = gn >> 7, d = gn & 127;
          ((u16*)outp)[((size_t)((bb * 16 + h) * 2048 + mm)) * 128 + d] = f2bf(v);
        } else if constexpr (EPI == 6) {
          ((float*)outp)[(size_t)gm * N + gn] =
              v + ((const float*)auxp)[(size_t)gm * N + gn];
        } else if constexpr (EPI == 7) {
          const float g = bf2f(((const u16*)auxp)[(size_t)gm * N + gn]);
          const float s = g / (1.0f + __expf(-g));
          ((u16*)outp)[(size_t)gm * N + gn] = f2bf(s * v);
        }
      }
    }
  }
}

// ---------------------------------------------------------------------------
// Flash attention, swapped-operand, LDS-staged, 32 m-rows per wave.
// Q,K:(B*NH, 2048, 192) bf16 (Q pre-scaled by SCALE*log2e, tails rope'd).
// VT:(B*NH, 128, 2048) bf16. O:(B, 2048, NH*128) bf16.
// ---------------------------------------------------------------------------
__global__ __launch_bounds__(256, 2) void flash_k(const u16* __restrict__ Q,
                                                  const u16* __restrict__ K,
                                                  const u16* __restrict__ VT,
                                                  u16* __restrict__ O) {
  __shared__ __attribute__((aligned(16))) u16 Ks[2][64 * 192];
  __shared__ __attribute__((aligned(16))) u16 Vs[128 * 64];

  const int t = threadIdx.x;
  const int wv = t >> 6, quad = (t >> 4) & 3, ln = t & 15;
  const int lane = t & 63;
  const int b = blockIdx.z, h = blockIdx.y;
  const int m0 = blockIdx.x * 128;
  const size_t qbase = ((size_t)(b * 16 + h)) * 2048;
  const u16* kg = K + qbase * 192;
  const u16* vg = VT + ((size_t)(b * 16 + h)) * 128 * 2048;

  // Per-thread staging coordinates (constants across j).
  int krow[6], kscol[6];               // K: row in tile, swizzled byte col
  #pragma unroll
  for (int i = 0; i < 6; ++i) {
    const int o = (wv * 6 + i) * 1024 + lane * 16;
    const int r = o / 384;
    const int c = o - r * 384;
    krow[i] = r;
    kscol[i] = c ^ ((r & 7) << 4);
  }
  int vrow[4], vscol[4];               // V: row (=d), swizzled byte col
  #pragma unroll
  for (int i = 0; i < 4; ++i) {
    const int o = (wv * 4 + i) * 1024 + lane * 16;
    const int r = o >> 7;
    vrow[i] = r;
    vscol[i] = (o & 127) ^ ((r & 7) << 4);
  }

  // Q fragments, two row groups.
  bf16x8 qfA[6], qfB[6];
  {
    const u16* qpA = Q + (qbase + m0 + wv * 16 + ln) * 192 + quad * 8;
    const u16* qpB = qpA + 64 * 192;
    #pragma unroll
    for (int ks = 0; ks < 6; ++ks) {
      qfA[ks] = *(const bf16x8*)&qpA[ks * 32];
      qfB[ks] = *(const bf16x8*)&qpB[ks * 32];
    }
  }

  float mA = -1e30f, lA = 0.0f, mB = -1e30f, lB = 0.0f;
  f32x4 ofA[8] = {}, ofB[8] = {};

  // prologue: stage tile 0 (K into buf 0, V)
  #pragma unroll
  for (int i = 0; i < 6; ++i)
    gload_lds16(kg + (size_t)krow[i] * 192 + (kscol[i] >> 1),
                &Ks[0][(wv * 6 + i) * 512 + lane * 8]);
  #pragma unroll
  for (int i = 0; i < 4; ++i)
    gload_lds16(vg + (size_t)vrow[i] * 2048 + (vscol[i] >> 1),
                &Vs[(wv * 4 + i) * 512 + lane * 8]);
  __syncthreads();

  int cur = 0;
  for (int j = 0; j < 32; ++j) {
    // prefetch next K tile into the other buffer
    if (j < 31) {
      #pragma unroll
      for (int i = 0; i < 6; ++i)
        gload_lds16(kg + (size_t)((j + 1) * 64 + krow[i]) * 192 + (kscol[i] >> 1),
                    &Ks[cur ^ 1][(wv * 6 + i) * 512 + lane * 8]);
    }

    // S^T tiles for both row groups: s[nt][r] = score(m, n = nt*16+quad*4+r)
    f32x4 sA[4], sB[4];
    #pragma unroll
    for (int nt = 0; nt < 4; ++nt) {
      f32x4 za = {0.f, 0.f, 0.f, 0.f}, zb = {0.f, 0.f, 0.f, 0.f};
      const int row = nt * 16 + ln;
      const u16* kr = &Ks[cur][row * 192];
      const int sw = (row & 7) << 4;
      #pragma unroll
      for (int ks = 0; ks < 6; ++ks) {
        bf16x8 kb = *(const bf16x8*)&kr[((ks * 64 + quad * 16) ^ sw) >> 1];
        za = mfma16(kb, qfA[ks], za);
        zb = mfma16(kb, qfB[ks], zb);
      }
      sA[nt] = za; sB[nt] = zb;
    }

    // online softmax (lane-local in m; scores already in log2 units)
    float mxA = sA[0][0], mxB = sB[0][0];
    #pragma unroll
    for (int nt = 0; nt < 4; ++nt)
      #pragma unroll
      for (int r = 0; r < 4; ++r) {
        mxA = fmaxf(mxA, sA[nt][r]);
        mxB = fmaxf(mxB, sB[nt][r]);
      }
    mxA = fmaxf(mxA, __shfl_xor(mxA, 16, 64));
    mxA = fmaxf(mxA, __shfl_xor(mxA, 32, 64));
    mxB = fmaxf(mxB, __shfl_xor(mxB, 16, 64));
    mxB = fmaxf(mxB, __shfl_xor(mxB, 32, 64));

    // defer-max: only rescale when the running max grew materially
    if (__any((mxA > mA + 11.0f) || (mxB > mB + 11.0f))) {
      const float mnA = fmaxf(mA, mxA), mnB = fmaxf(mB, mxB);
      const float aA = exp2f(mA - mnA), aB = exp2f(mB - mnB);
      mA = mnA; mB = mnB;
      lA *= aA; lB *= aB;
      #pragma unroll
      for (int dt = 0; dt < 8; ++dt)
        #pragma unroll
        for (int r = 0; r < 4; ++r) {
          ofA[dt][r] *= aA;
          ofB[dt][r] *= aB;
        }
    }

    float rsA = 0.0f, rsB = 0.0f;
    #pragma unroll
    for (int nt = 0; nt < 4; ++nt)
      #pragma unroll
      for (int r = 0; r < 4; ++r) {
        const float pa = exp2f(sA[nt][r] - mA);
        const float pb = exp2f(sB[nt][r] - mB);
        sA[nt][r] = pa; sB[nt][r] = pb;
        rsA += pa; rsB += pb;
      }
    rsA += __shfl_xor(rsA, 16, 64);
    rsA += __shfl_xor(rsA, 32, 64);
    rsB += __shfl_xor(rsB, 16, 64);
    rsB += __shfl_xor(rsB, 32, 64);
    lA += rsA; lB += rsB;

    // pack P rows to bf16 pairs (hardware packed convert)
    unsigned pkA[4][2], pkB[4][2];
    #pragma unroll
    for (int nt = 0; nt < 4; ++nt) {
      pkA[nt][0] = cvt_pk_bf16(sA[nt][0], sA[nt][1]);
      pkA[nt][1] = cvt_pk_bf16(sA[nt][2], sA[nt][3]);
      pkB[nt][0] = cvt_pk_bf16(sB[nt][0], sB[nt][1]);
      pkB[nt][1] = cvt_pk_bf16(sB[nt][2], sB[nt][3]);
    }
    // cross-quad redistribute into PV B-fragment layout (verified R4 mapping)
    unsigned pawA[2][4], pawB[2][4];
    #pragma unroll
    for (int kt = 0; kt < 2; ++kt)
      #pragma unroll
      for (int w = 0; w < 4; ++w) {
        const int src = ((quad & 1) * 2 + (w >> 1)) * 16 + ln;
        const int loA = __shfl((int)pkA[2 * kt][w & 1], src, 64);
        const int hiA = __shfl((int)pkA[2 * kt + 1][w & 1], src, 64);
        pawA[kt][w] = (unsigned)((quad & 2) ? hiA : loA);
        const int loB = __shfl((int)pkB[2 * kt][w & 1], src, 64);
        const int hiB = __shfl((int)pkB[2 * kt + 1][w & 1], src, 64);
        pawB[kt][w] = (unsigned)((quad & 2) ? hiB : loB);
      }

    __syncthreads();   // V(j) staged (vmcnt drained) before PV reads

    // PV: of[dt][r] = out[m][d = dt*16 + quad*4 + r]
    #pragma unroll
    for (int kt = 0; kt < 2; ++kt) {
      union { unsigned u[4]; bf16x8 b; } paA, paB;
      #pragma unroll
      for (int w = 0; w < 4; ++w) { paA.u[w] = pawA[kt][w]; paB.u[w] = pawB[kt][w]; }
      #pragma unroll
      for (int dt = 0; dt < 8; ++dt) {
        const int row = dt * 16 + ln;
        const int sw = (row & 7) << 4;
        bf16x8 vb = *(const bf16x8*)&Vs[row * 64 +
                                        (((kt * 64 + quad * 16) ^ sw) >> 1)];
        ofA[dt] = mfma16(vb, paA.b, ofA[dt]);
        ofB[dt] = mfma16(vb, paB.b, ofB[dt]);
      }
    }

    __syncthreads();   // all waves done reading Vs -> safe to overwrite

    if (j < 31) {
      #pragma unroll
      for (int i = 0; i < 4; ++i)
        gload_lds16(vg + (size_t)vrow[i] * 2048 + (j + 1) * 64 + (vscol[i] >> 1),
                    &Vs[(wv * 4 + i) * 512 + lane * 8]);
    }
    cur ^= 1;
  }

  const float invA = 1.0f / lA, invB = 1.0f / lB;
  #pragma unroll
  for (int dt = 0; dt < 8; ++dt) {
    u16x4 oa, ob;
    #pragma unroll
    for (int r = 0; r < 4; ++r) {
      oa[r] = f2bf(ofA[dt][r] * invA);
      ob[r] = f2bf(ofB[dt][r] * invB);
    }
    *(u16x4*)&O[((size_t)(b * 2048 + m0 + wv * 16 + ln)) * 2048 +
                h * 128 + dt * 16 + quad * 4] = oa;
    *(u16x4*)&O[((size_t)(b * 2048 + m0 + 64 + wv * 16 + ln)) * 2048 +
                h * 128 + dt * 16 + quad * 4] = ob;
  }
}

// ---------------------------------------------------------------------------
// Launch. Workspace layout (MiB offsets), phase-aliased, peak 104 MiB.
// ---------------------------------------------------------------------------
extern "C" void kernel_launch(void* const* d_in, const int* in_sizes, int n_in,
                              void* d_out, int out_size, void* d_ws, size_t ws_size,
                              hipStream_t stream) {
  const float* query     = (const float*)d_in[0];
  const float* key_value = (const float*)d_in[1];
  const float* g_q       = (const float*)d_in[2];
  const float* g_kv      = (const float*)d_in[3];
  const float* g_ffn     = (const float*)d_in[4];
  const float* w_qc      = (const float*)d_in[5];
  const float* w_kc      = (const float*)d_in[6];
  const float* w_qr      = (const float*)d_in[7];
  const float* w_kr      = (const float*)d_in[8];
  const float* w_v       = (const float*)d_in[9];
  const float* w_o       = (const float*)d_in[10];
  const float* w_gate    = (const float*)d_in[11];
  const float* w_up      = (const float*)d_in[12];
  const float* w_down    = (const float*)d_in[13];

  char* ws = (char*)d_ws;
  const size_t MiB = 1048576;
  u16*   qn   = (u16*)(ws + 0 * MiB);
  u16*   kvn  = (u16*)(ws + 16 * MiB);
  u16*   Qb   = (u16*)(ws + 32 * MiB);
  u16*   Kb   = (u16*)(ws + 56 * MiB);
  u16*   Vb   = (u16*)(ws + 80 * MiB);
  u16*   wt   = (u16*)(ws + 96 * MiB);   // 8 MiB slab (proj weights)
  u16*   VT   = (u16*)(ws + 0 * MiB);    // over qn (dead)
  u16*   attn = (u16*)(ws + 16 * MiB);   // over kvn (dead)
  float* x    = (float*)(ws + 64 * MiB); // over Kb-tail+Vb (dead)
  u16*   xn   = (u16*)(ws + 0 * MiB);    // over VT (dead)
  u16*   ghalf= (u16*)(ws + 16 * MiB);   // over attn+Qb-head (dead), 32 MiB
  u16*   wtf  = (u16*)(ws + 48 * MiB);   // over Qb-tail+Kb-head (dead), 16 MiB

  const dim3 blk(256);

  // input norms
  rmsnorm_k<<<4096, blk, 0, stream>>>(query, g_q, qn);
  rmsnorm_k<<<4096, blk, 0, stream>>>(key_value, g_kv, kvn);

  // Q projections (qn dead after these)
  conv_t<<<dim3(32, 32), blk, 0, stream>>>(w_qc, wt, 2048, 2048, 2048);
  gemm_bt<1><<<dim3(16, 32), blk, 0, stream>>>(qn, wt, 2048, 2048, Qb, nullptr);
  conv_t<<<dim3(16, 32), blk, 0, stream>>>(w_qr, wt, 2048, 1024, 1024);
  gemm_bt<2><<<dim3(8, 32), blk, 0, stream>>>(qn, wt, 1024, 2048, Qb, nullptr);
  // K projections
  conv_t<<<dim3(32, 32), blk, 0, stream>>>(w_kc, wt, 2048, 2048, 2048);
  gemm_bt<3><<<dim3(16, 32), blk, 0, stream>>>(kvn, wt, 2048, 2048, Kb, nullptr);
  conv_t<<<dim3(16, 32), blk, 0, stream>>>(w_kr, wt, 2048, 1024, 1024);
  gemm_bt<4><<<dim3(8, 32), blk, 0, stream>>>(kvn, wt, 1024, 2048, Kb, nullptr);
  // V projection (kvn dead after)
  conv_t<<<dim3(32, 32), blk, 0, stream>>>(w_v, wt, 2048, 2048, 2048);
  gemm_bt<5><<<dim3(16, 32), blk, 0, stream>>>(kvn, wt, 2048, 2048, Vb, nullptr);

  // RoPE tails
  rope_k<<<8192, blk, 0, stream>>>(Qb);
  rope_k<<<8192, blk, 0, stream>>>(Kb);

  // V -> V^T per head (Vb -> VT; VT aliases dead qn)
  transpose_bf16<<<dim3(2, 32, 32), blk, 0, stream>>>(Vb, VT, 2048, 128);

  // flash attention -> attn (aliases dead kvn)
  flash_k<<<dim3(16, 16, 2), blk, 0, stream>>>(Qb, Kb, VT, attn);

  // out projection + residual -> x fp32 (aliases dead Kb-tail/Vb)
  conv_t<<<dim3(32, 32), blk, 0, stream>>>(w_o, wt, 2048, 2048, 2048);
  gemm_bt<6><<<dim3(16, 32), blk, 0, stream>>>(attn, wt, 2048, 2048, x, query);

  // FFN: rmsnorm then two N=4096 halves with split-K accumulation into d_out
  rmsnorm_k<<<4096, blk, 0, stream>>>(x, g_ffn, xn);
  for (int h = 0; h < 2; ++h) {
    const int n0 = h * 4096;
    conv_t<<<dim3(64, 32), blk, 0, stream>>>(w_gate + n0, wtf, 2048, 4096, 8192);
    gemm_bt<0><<<dim3(32, 32), blk, 0, stream>>>(xn, wtf, 4096, 2048, ghalf, nullptr);
    conv_t<<<dim3(64, 32), blk, 0, stream>>>(w_up + n0, wtf, 2048, 4096, 8192);
    gemm_bt<7><<<dim3(32, 32), blk, 0, stream>>>(xn, wtf, 4096, 2048, ghalf, ghalf);
    conv_t<<<dim3(32, 64), blk, 0, stream>>>(w_down + (size_t)n0 * 2048, wtf,
                                             4096, 2048, 2048);
    gemm_bt<6><<<dim3(16, 32), blk, 0, stream>>>(ghalf, wtf, 2048, 4096,
                                                 (float*)d_out,
                                                 h == 0 ? (const void*)x
                                                        : (const void*)d_out);
  }
}

// Round 4
// 1258.194 us; speedup vs baseline: 1.5077x; 1.0571x over previous
//
#include <hip/hip_runtime.h>
#include <stdint.h>

// ---------------------------------------------------------------------------
// AttentionBlock (MLA-style) on gfx950. Round 7:
//   - NEW gemm256: 256x256 tile, 8 waves (512 thr), BK=64, full-tile LDS
//     double-buffer (128 KiB), 3-phase K-loop with raw s_barrier (no
//     __syncthreads vmcnt(0) drain), stages front-loaded in phases 1-2,
//     single counted vmcnt(0) drain per K-tile ~2.5 phases after issue,
//     setprio(1) around MFMA clusters, XOR-swizzled LDS (proven pattern).
//     Used for the two FFN N=4096 GEMMs (grid 16x16 = 256 blocks = 1/CU).
//   - everything else identical to R6 (passed, 1330 us).
// ---------------------------------------------------------------------------

typedef unsigned short u16;
typedef __bf16 bf16x8 __attribute__((ext_vector_type(8)));
typedef unsigned short u16x8 __attribute__((ext_vector_type(8)));
typedef unsigned short u16x4 __attribute__((ext_vector_type(4)));
typedef float f32x4 __attribute__((ext_vector_type(4)));

#define LOG2E 1.4426950408889634f
#define SCALE_F 0.07216878364870323f   // 1/sqrt(128+64)

__device__ __forceinline__ f32x4 mfma16(bf16x8 a, bf16x8 b, f32x4 c) {
  return __builtin_amdgcn_mfma_f32_16x16x32_bf16(a, b, c, 0, 0, 0);
}

__device__ __forceinline__ u16 f2bf(float f) {
  union { float f; unsigned u; } x; x.f = f;
  unsigned r = x.u + 0x7fffu + ((x.u >> 16) & 1u);  // RNE
  return (u16)(r >> 16);
}
__device__ __forceinline__ float bf2f(u16 v) {
  union { unsigned u; float f; } x; x.u = ((unsigned)v) << 16;
  return x.f;
}
// packed f32x2 -> bf16x2 (hardware RNE), gfx950
__device__ __forceinline__ unsigned cvt_pk_bf16(float lo, float hi) {
  unsigned r;
  asm("v_cvt_pk_bf16_f32 %0, %1, %2" : "=v"(r) : "v"(lo), "v"(hi));
  return r;
}

// async global->LDS, 16 bytes per lane. LDS dest is wave-uniform base +
// lane*16 (linear); caller passes per-lane pointer equal to that.
__device__ __forceinline__ void gload_lds16(const u16* g, u16* l) {
  __builtin_amdgcn_global_load_lds(
      (const __attribute__((address_space(1))) unsigned int*)g,
      (__attribute__((address_space(3))) unsigned int*)l, 16, 0, 0);
}

// raw workgroup barrier with compile-time motion fences (no vmcnt drain!)
__device__ __forceinline__ void sbar() {
  __builtin_amdgcn_sched_barrier(0);
  __builtin_amdgcn_s_barrier();
  __builtin_amdgcn_sched_barrier(0);
}

// ---------------------------------------------------------------------------
// RMSNorm: one 256-thread block per row of 2048 fp32. Output bf16.
// ---------------------------------------------------------------------------
__global__ __launch_bounds__(256) void rmsnorm_k(const float* __restrict__ x,
                                                 const float* __restrict__ g,
                                                 u16* __restrict__ out) {
  const int row = blockIdx.x;
  const int t = threadIdx.x;
  const float* xr = x + (size_t)row * 2048;
  float4 a = ((const float4*)xr)[t * 2];
  float4 b = ((const float4*)xr)[t * 2 + 1];
  float ss = a.x*a.x + a.y*a.y + a.z*a.z + a.w*a.w
           + b.x*b.x + b.y*b.y + b.z*b.z + b.w*b.w;
  #pragma unroll
  for (int off = 32; off; off >>= 1) ss += __shfl_xor(ss, off, 64);
  __shared__ float w4[4];
  if ((t & 63) == 0) w4[t >> 6] = ss;
  __syncthreads();
  ss = w4[0] + w4[1] + w4[2] + w4[3];
  const float n = rsqrtf(ss * (1.0f / 2048.0f) + 1e-6f);
  const float* gr = g + t * 8;
  u16x8 o;
  o[0] = f2bf(a.x * n * gr[0]); o[1] = f2bf(a.y * n * gr[1]);
  o[2] = f2bf(a.z * n * gr[2]); o[3] = f2bf(a.w * n * gr[3]);
  o[4] = f2bf(b.x * n * gr[4]); o[5] = f2bf(b.y * n * gr[5]);
  o[6] = f2bf(b.z * n * gr[6]); o[7] = f2bf(b.w * n * gr[7]);
  *(u16x8*)&out[(size_t)row * 2048 + t * 8] = o;
}

// ---------------------------------------------------------------------------
// Transpose-convert fp32 (R x C slab, row stride ldin) -> bf16 (C x R).
// ---------------------------------------------------------------------------
__global__ __launch_bounds__(256) void conv_t(const float* __restrict__ in,
                                              u16* __restrict__ out,
                                              int R, int C, int ldin) {
  __shared__ float tile[64][65];
  const int r0 = blockIdx.y * 64, c0 = blockIdx.x * 64;
  const int tr = threadIdx.x >> 6, tc = threadIdx.x & 63;
  #pragma unroll
  for (int i = 0; i < 16; ++i) {
    int rr = tr * 16 + i;
    tile[rr][tc] = in[(size_t)(r0 + rr) * ldin + c0 + tc];
  }
  __syncthreads();
  #pragma unroll
  for (int i = 0; i < 16; ++i) {
    int rr = tr * 16 + i;
    out[(size_t)(c0 + rr) * R + r0 + tc] = f2bf(tile[tc][rr]);
  }
}

// bf16 (R x C) -> bf16 (C x R), batched over blockIdx.z (stride R*C).
__global__ __launch_bounds__(256) void transpose_bf16(const u16* __restrict__ in,
                                                      u16* __restrict__ out,
                                                      int R, int C) {
  __shared__ u16 tile[64][65];
  const size_t zoff = (size_t)blockIdx.z * R * C;
  const u16* inz = in + zoff;
  u16* outz = out + zoff;
  const int r0 = blockIdx.y * 64, c0 = blockIdx.x * 64;
  const int tr = threadIdx.x >> 6, tc = threadIdx.x & 63;
  #pragma unroll
  for (int i = 0; i < 16; ++i) {
    int rr = tr * 16 + i;
    tile[rr][tc] = inz[(size_t)(r0 + rr) * C + c0 + tc];
  }
  __syncthreads();
  #pragma unroll
  for (int i = 0; i < 16; ++i) {
    int rr = tr * 16 + i;
    outz[(size_t)(c0 + rr) * R + r0 + tc] = tile[tc][rr];
  }
}

// ---------------------------------------------------------------------------
// RoPE in-place on cols [128,192) of a (B*NH, 2048, 192) bf16 buffer.
// ---------------------------------------------------------------------------
__global__ __launch_bounds__(256) void rope_k(u16* __restrict__ buf) {
  const int idx = blockIdx.x * 256 + threadIdx.x;
  const int i = idx & 31;
  const int pos = (idx >> 5) & 2047;
  const int bh = idx >> 16;            // 0..31
  u16* p = buf + ((size_t)(bh * 2048 + pos)) * 192 + 128 + 2 * i;
  const float inv = exp2f(-(float)(2 * i) * (19.931568569324174f / 64.0f));
  const float f = (float)pos * inv;
  const float c = cosf(f), s = sinf(f);
  const float x1 = bf2f(p[0]), x2 = bf2f(p[1]);
  p[0] = f2bf(x1 * c - x2 * s);
  p[1] = f2bf(x2 * c + x1 * s);
}

// ---------------------------------------------------------------------------
// bf16 GEMM (128x128 tile): C(MxN) = A(MxK,rm) * Bt(NxK,rm)^T.  BK=64,
// XOR-swizzled LDS, global_load_lds staging, XCD-swizzled grid. Proven R6.
// ---------------------------------------------------------------------------
template <int EPI>
__global__ __launch_bounds__(256) void gemm_bt(const u16* __restrict__ A,
                                               const u16* __restrict__ Bt,
                                               int N, int K,
                                               void* __restrict__ outp,
                                               const void* __restrict__ auxp) {
  __shared__ __attribute__((aligned(16))) u16 As[128 * 64];
  __shared__ __attribute__((aligned(16))) u16 Bs[128 * 64];
  const int t = threadIdx.x;
  const int wv = t >> 6, quad = (t >> 4) & 3, ln = t & 15;

  const int nbx = gridDim.x;
  const int lin = blockIdx.y * nbx + blockIdx.x;
  const int cpx = (nbx * gridDim.y) >> 3;
  const int swz = (lin & 7) * cpx + (lin >> 3);
  const int bm0 = (swz / nbx) * 128, bn0 = (swz % nbx) * 128;
  const int wm = (wv >> 1) * 64, wn = (wv & 1) * 64;

  f32x4 acc[4][4] = {};

  int srow[4], scol[4];
  #pragma unroll
  for (int i = 0; i < 4; ++i) {
    const int row = i * 32 + (t >> 3);
    const int cB = ((t & 7) * 16) ^ ((row & 7) << 4);
    srow[i] = row;
    scol[i] = cB >> 1;
  }

  for (int kk = 0; kk < K; kk += 64) {
    #pragma unroll
    for (int i = 0; i < 4; ++i) {
      gload_lds16(&A[(size_t)(bm0 + srow[i]) * K + kk + scol[i]],
                  &As[i * 2048 + t * 8]);
      gload_lds16(&Bt[(size_t)(bn0 + srow[i]) * K + kk + scol[i]],
                  &Bs[i * 2048 + t * 8]);
    }
    __syncthreads();
    #pragma unroll
    for (int ks = 0; ks < 2; ++ks) {
      bf16x8 af[4], bfr[4];
      #pragma unroll
      for (int mt = 0; mt < 4; ++mt) {
        const int row = wm + mt * 16 + ln;
        af[mt] = *(const bf16x8*)&As[row * 64 +
                   (((ks * 64 + quad * 16) ^ ((row & 7) << 4)) >> 1)];
      }
      #pragma unroll
      for (int nt = 0; nt < 4; ++nt) {
        const int row = wn + nt * 16 + ln;
        bfr[nt] = *(const bf16x8*)&Bs[row * 64 +
                   (((ks * 64 + quad * 16) ^ ((row & 7) << 4)) >> 1)];
      }
      #pragma unroll
      for (int mt = 0; mt < 4; ++mt)
        #pragma unroll
        for (int nt = 0; nt < 4; ++nt)
          acc[mt][nt] = mfma16(af[mt], bfr[nt], acc[mt][nt]);
    }
    __syncthreads();
  }

  #pragma unroll
  for (int mt = 0; mt < 4; ++mt) {
    #pragma unroll
    for (int r = 0; r < 4; ++r) {
      const int gm = bm0 + wm + mt * 16 + quad * 4 + r;
      #pragma unroll
      for (int nt = 0; nt < 4; ++nt) {
        const int gn = bn0 + wn + nt * 16 + ln;
        float v = acc[mt][nt][r];
        if constexpr (EPI == 0) {
          ((u16*)outp)[(size_t)gm * N + gn] = f2bf(v);
        } else if constexpr (EPI >= 1 && EPI <= 4) {
          if constexpr (EPI == 1 || EPI == 2) v *= SCALE_F * LOG2E;
          const int bb = gm >> 11, mm = gm & 2047;
          int h, d, off;
          if constexpr (EPI == 1 || EPI == 3) { h = gn >> 7; d = gn & 127; off = 0; }
          else                                { h = gn >> 6; d = gn & 63; off = 128; }
          ((u16*)outp)[((size_t)((bb * 16 + h) * 2048 + mm)) * 192 + off + d] = f2bf(v);
        } else if constexpr (EPI == 5) {
          const int bb = gm >> 11, mm = gm & 2047;
          const int h = gn >> 7, d = gn & 127;
          ((u16*)outp)[((size_t)((bb * 16 + h) * 2048 + mm)) * 128 + d] = f2bf(v);
        } else if constexpr (EPI == 6) {
          ((float*)outp)[(size_t)gm * N + gn] =
              v + ((const float*)auxp)[(size_t)gm * N + gn];
        } else if constexpr (EPI == 7) {
          const float g = bf2f(((const u16*)auxp)[(size_t)gm * N + gn]);
          const float s = g / (1.0f + __expf(-g));
          ((u16*)outp)[(size_t)gm * N + gn] = f2bf(s * v);
        }
      }
    }
  }
}

// ---------------------------------------------------------------------------
// bf16 GEMM, 256x256 tile, 8 waves (512 thr), BK=64, deep-pipelined 3-phase.
// Wave (wm=wv>>2, wn=wv&3) owns m-frags mt=0..7 (rows (mt>>2)*128+wm*64+
// (mt&3)*16) x n-frags nt=0..3 (cols (nt>>1)*128+wn*32+(nt&1)*16).
// LDS: 2 tile-buffers x 2 halves x (128x64) per matrix = 128 KiB total.
// Per K-tile: P1 {stage A(t+1); read A03+B01; 16 MFMA} P2 {stage B(t+1);
// read B23; 16 MFMA} P3 {read A47; 32 MFMA; vmcnt(0)}, raw s_barrier between
// phases. Full-tile dbuf => no overwrite hazard; vmcnt(0) sits ~2.5 phases
// after the last stage issue, so the drain is mostly amortized.
// ---------------------------------------------------------------------------
template <int EPI>
__global__ __launch_bounds__(512, 2) void gemm256(const u16* __restrict__ A,
                                                  const u16* __restrict__ Bt,
                                                  int N, int K,
                                                  void* __restrict__ outp,
                                                  const void* __restrict__ auxp) {
  __shared__ __attribute__((aligned(16))) u16 As[2][2][128 * 64];
  __shared__ __attribute__((aligned(16))) u16 Bs[2][2][128 * 64];
  const int t = threadIdx.x;
  const int wv = t >> 6, quad = (t >> 4) & 3, ln = t & 15;
  const int wm = wv >> 2, wn = wv & 3;

  const int nbx = gridDim.x;
  const int lin = blockIdx.y * nbx + blockIdx.x;
  const int cpx = (nbx * gridDim.y) >> 3;
  const int swz = (lin & 7) * cpx + (lin >> 3);
  const int bm0 = (swz / nbx) * 256, bn0 = (swz % nbx) * 256;

  f32x4 acc[8][4] = {};

  // staging coords: per half-tile (128 rows x 128 B), thread covers physical
  // bytes o = i*8192 + t*16 (i=0,1); source col pre-swizzled (rule #21).
  int srow[2], scol[2];
  #pragma unroll
  for (int i = 0; i < 2; ++i) {
    const int o = i * 8192 + t * 16;
    const int r = o >> 7;
    srow[i] = r;
    scol[i] = ((o & 127) ^ ((r & 7) << 4)) >> 1;
  }

  // prologue: stage tile 0 (A then B), drain, barrier
  #pragma unroll
  for (int hf = 0; hf < 2; ++hf)
    #pragma unroll
    for (int i = 0; i < 2; ++i)
      gload_lds16(&A[(size_t)(bm0 + hf * 128 + srow[i]) * K + scol[i]],
                  &As[0][hf][i * 4096 + t * 8]);
  #pragma unroll
  for (int hf = 0; hf < 2; ++hf)
    #pragma unroll
    for (int i = 0; i < 2; ++i)
      gload_lds16(&Bt[(size_t)(bn0 + hf * 128 + srow[i]) * K + scol[i]],
                  &Bs[0][hf][i * 4096 + t * 8]);
  asm volatile("s_waitcnt vmcnt(0)" ::: "memory");
  sbar();

  const int NT = K >> 6;
  for (int kt = 0; kt < NT; ++kt) {
    const int bsel = kt & 1;
    const u16* A0 = As[bsel][0];
    const u16* A1 = As[bsel][1];
    const u16* B0 = Bs[bsel][0];
    const u16* B1 = Bs[bsel][1];
    const bool pf = (kt + 1 < NT);
    const int knext = (kt + 1) * 64;

    bf16x8 af[2][4], bfr[2][4];

    // ---- P1: stage A(t+1) | read A03 + B01 | MFMA 16 ----
    if (pf) {
      #pragma unroll
      for (int hf = 0; hf < 2; ++hf)
        #pragma unroll
        for (int i = 0; i < 2; ++i)
          gload_lds16(&A[(size_t)(bm0 + hf * 128 + srow[i]) * K + knext + scol[i]],
                      &As[bsel ^ 1][hf][i * 4096 + t * 8]);
    }
    #pragma unroll
    for (int mt = 0; mt < 4; ++mt) {
      const int row = wm * 64 + mt * 16 + ln;
      const int sw = (row & 7) << 4;
      #pragma unroll
      for (int ks = 0; ks < 2; ++ks)
        af[ks][mt] = *(const bf16x8*)&A0[row * 64 +
                       (((ks * 64 + quad * 16) ^ sw) >> 1)];
    }
    #pragma unroll
    for (int nt = 0; nt < 2; ++nt) {
      const int row = wn * 32 + nt * 16 + ln;
      const int sw = (row & 7) << 4;
      #pragma unroll
      for (int ks = 0; ks < 2; ++ks)
        bfr[ks][nt] = *(const bf16x8*)&B0[row * 64 +
                        (((ks * 64 + quad * 16) ^ sw) >> 1)];
    }
    __builtin_amdgcn_s_setprio(1);
    #pragma unroll
    for (int mt = 0; mt < 4; ++mt)
      #pragma unroll
      for (int nt = 0; nt < 2; ++nt)
        #pragma unroll
        for (int ks = 0; ks < 2; ++ks)
          acc[mt][nt] = mfma16(af[ks][mt], bfr[ks][nt], acc[mt][nt]);
    __builtin_amdgcn_s_setprio(0);
    sbar();

    // ---- P2: stage B(t+1) | read B23 | MFMA 16 ----
    if (pf) {
      #pragma unroll
      for (int hf = 0; hf < 2; ++hf)
        #pragma unroll
        for (int i = 0; i < 2; ++i)
          gload_lds16(&Bt[(size_t)(bn0 + hf * 128 + srow[i]) * K + knext + scol[i]],
                      &Bs[bsel ^ 1][hf][i * 4096 + t * 8]);
    }
    #pragma unroll
    for (int nt = 2; nt < 4; ++nt) {
      const int row = wn * 32 + (nt & 1) * 16 + ln;
      const int sw = (row & 7) << 4;
      #pragma unroll
      for (int ks = 0; ks < 2; ++ks)
        bfr[ks][nt] = *(const bf16x8*)&B1[row * 64 +
                        (((ks * 64 + quad * 16) ^ sw) >> 1)];
    }
    __builtin_amdgcn_s_setprio(1);
    #pragma unroll
    for (int mt = 0; mt < 4; ++mt)
      #pragma unroll
      for (int nt = 2; nt < 4; ++nt)
        #pragma unroll
        for (int ks = 0; ks < 2; ++ks)
          acc[mt][nt] = mfma16(af[ks][mt], bfr[ks][nt], acc[mt][nt]);
    __builtin_amdgcn_s_setprio(0);
    sbar();

    // ---- P3: read A47 | MFMA 32 | drain stages | barrier ----
    #pragma unroll
    for (int mt = 0; mt < 4; ++mt) {
      const int row = wm * 64 + mt * 16 + ln;
      const int sw = (row & 7) << 4;
      #pragma unroll
      for (int ks = 0; ks < 2; ++ks)
        af[ks][mt] = *(const bf16x8*)&A1[row * 64 +
                       (((ks * 64 + quad * 16) ^ sw) >> 1)];
    }
    __builtin_amdgcn_s_setprio(1);
    #pragma unroll
    for (int mt = 0; mt < 4; ++mt)
      #pragma unroll
      for (int nt = 0; nt < 4; ++nt)
        #pragma unroll
        for (int ks = 0; ks < 2; ++ks)
          acc[mt + 4][nt] = mfma16(af[ks][mt], bfr[ks][nt], acc[mt + 4][nt]);
    __builtin_amdgcn_s_setprio(0);
    if (pf) asm volatile("s_waitcnt vmcnt(0)" ::: "memory");
    sbar();
  }

  // epilogue
  #pragma unroll
  for (int mt = 0; mt < 8; ++mt) {
    #pragma unroll
    for (int r = 0; r < 4; ++r) {
      const int gm = bm0 + (mt >> 2) * 128 + wm * 64 + (mt & 3) * 16 + quad * 4 + r;
      #pragma unroll
      for (int nt = 0; nt < 4; ++nt) {
        const int gn = bn0 + (nt >> 1) * 128 + wn * 32 + (nt & 1) * 16 + ln;
        float v = acc[mt][nt][r];
        if constexpr (EPI == 0) {
          ((u16*)outp)[(size_t)gm * N + gn] = f2bf(v);
        } else if constexpr (EPI == 7) {
          const float g = bf2f(((const u16*)auxp)[(size_t)gm * N + gn]);
          const float s = g / (1.0f + __expf(-g));
          ((u16*)outp)[(size_t)gm * N + gn] = f2bf(s * v);
        }
      }
    }
  }
}

// ---------------------------------------------------------------------------
// Flash attention, swapped-operand, LDS-staged, 32 m-rows per wave. (R5/R6)
// ---------------------------------------------------------------------------
__global__ __launch_bounds__(256, 2) void flash_k(const u16* __restrict__ Q,
                                                  const u16* __restrict__ K,
                                                  const u16* __restrict__ VT,
                                                  u16* __restrict__ O) {
  __shared__ __attribute__((aligned(16))) u16 Ks[2][64 * 192];
  __shared__ __attribute__((aligned(16))) u16 Vs[128 * 64];

  const int t = threadIdx.x;
  const int wv = t >> 6, quad = (t >> 4) & 3, ln = t & 15;
  const int lane = t & 63;
  const int b = blockIdx.z, h = blockIdx.y;
  const int m0 = blockIdx.x * 128;
  const size_t qbase = ((size_t)(b * 16 + h)) * 2048;
  const u16* kg = K + qbase * 192;
  const u16* vg = VT + ((size_t)(b * 16 + h)) * 128 * 2048;

  int krow[6], kscol[6];
  #pragma unroll
  for (int i = 0; i < 6; ++i) {
    const int o = (wv * 6 + i) * 1024 + lane * 16;
    const int r = o / 384;
    const int c = o - r * 384;
    krow[i] = r;
    kscol[i] = c ^ ((r & 7) << 4);
  }
  int vrow[4], vscol[4];
  #pragma unroll
  for (int i = 0; i < 4; ++i) {
    const int o = (wv * 4 + i) * 1024 + lane * 16;
    const int r = o >> 7;
    vrow[i] = r;
    vscol[i] = (o & 127) ^ ((r & 7) << 4);
  }

  bf16x8 qfA[6], qfB[6];
  {
    const u16* qpA = Q + (qbase + m0 + wv * 16 + ln) * 192 + quad * 8;
    const u16* qpB = qpA + 64 * 192;
    #pragma unroll
    for (int ks = 0; ks < 6; ++ks) {
      qfA[ks] = *(const bf16x8*)&qpA[ks * 32];
      qfB[ks] = *(const bf16x8*)&qpB[ks * 32];
    }
  }

  float mA = -1e30f, lA = 0.0f, mB = -1e30f, lB = 0.0f;
  f32x4 ofA[8] = {}, ofB[8] = {};

  #pragma unroll
  for (int i = 0; i < 6; ++i)
    gload_lds16(kg + (size_t)krow[i] * 192 + (kscol[i] >> 1),
                &Ks[0][(wv * 6 + i) * 512 + lane * 8]);
  #pragma unroll
  for (int i = 0; i < 4; ++i)
    gload_lds16(vg + (size_t)vrow[i] * 2048 + (vscol[i] >> 1),
                &Vs[(wv * 4 + i) * 512 + lane * 8]);
  __syncthreads();

  int cur = 0;
  for (int j = 0; j < 32; ++j) {
    if (j < 31) {
      #pragma unroll
      for (int i = 0; i < 6; ++i)
        gload_lds16(kg + (size_t)((j + 1) * 64 + krow[i]) * 192 + (kscol[i] >> 1),
                    &Ks[cur ^ 1][(wv * 6 + i) * 512 + lane * 8]);
    }

    f32x4 sA[4], sB[4];
    #pragma unroll
    for (int nt = 0; nt < 4; ++nt) {
      f32x4 za = {0.f, 0.f, 0.f, 0.f}, zb = {0.f, 0.f, 0.f, 0.f};
      const int row = nt * 16 + ln;
      const u16* kr = &Ks[cur][row * 192];
      const int sw = (row & 7) << 4;
      #pragma unroll
      for (int ks = 0; ks < 6; ++ks) {
        bf16x8 kb = *(const bf16x8*)&kr[((ks * 64 + quad * 16) ^ sw) >> 1];
        za = mfma16(kb, qfA[ks], za);
        zb = mfma16(kb, qfB[ks], zb);
      }
      sA[nt] = za; sB[nt] = zb;
    }

    float mxA = sA[0][0], mxB = sB[0][0];
    #pragma unroll
    for (int nt = 0; nt < 4; ++nt)
      #pragma unroll
      for (int r = 0; r < 4; ++r) {
        mxA = fmaxf(mxA, sA[nt][r]);
        mxB = fmaxf(mxB, sB[nt][r]);
      }
    mxA = fmaxf(mxA, __shfl_xor(mxA, 16, 64));
    mxA = fmaxf(mxA, __shfl_xor(mxA, 32, 64));
    mxB = fmaxf(mxB, __shfl_xor(mxB, 16, 64));
    mxB = fmaxf(mxB, __shfl_xor(mxB, 32, 64));

    if (__any((mxA > mA + 11.0f) || (mxB > mB + 11.0f))) {
      const float mnA = fmaxf(mA, mxA), mnB = fmaxf(mB, mxB);
      const float aA = exp2f(mA - mnA), aB = exp2f(mB - mnB);
      mA = mnA; mB = mnB;
      lA *= aA; lB *= aB;
      #pragma unroll
      for (int dt = 0; dt < 8; ++dt)
        #pragma unroll
        for (int r = 0; r < 4; ++r) {
          ofA[dt][r] *= aA;
          ofB[dt][r] *= aB;
        }
    }

    float rsA = 0.0f, rsB = 0.0f;
    #pragma unroll
    for (int nt = 0; nt < 4; ++nt)
      #pragma unroll
      for (int r = 0; r < 4; ++r) {
        const float pa = exp2f(sA[nt][r] - mA);
        const float pb = exp2f(sB[nt][r] - mB);
        sA[nt][r] = pa; sB[nt][r] = pb;
        rsA += pa; rsB += pb;
      }
    rsA += __shfl_xor(rsA, 16, 64);
    rsA += __shfl_xor(rsA, 32, 64);
    rsB += __shfl_xor(rsB, 16, 64);
    rsB += __shfl_xor(rsB, 32, 64);
    lA += rsA; lB += rsB;

    unsigned pkA[4][2], pkB[4][2];
    #pragma unroll
    for (int nt = 0; nt < 4; ++nt) {
      pkA[nt][0] = cvt_pk_bf16(sA[nt][0], sA[nt][1]);
      pkA[nt][1] = cvt_pk_bf16(sA[nt][2], sA[nt][3]);
      pkB[nt][0] = cvt_pk_bf16(sB[nt][0], sB[nt][1]);
      pkB[nt][1] = cvt_pk_bf16(sB[nt][2], sB[nt][3]);
    }
    unsigned pawA[2][4], pawB[2][4];
    #pragma unroll
    for (int kt = 0; kt < 2; ++kt)
      #pragma unroll
      for (int w = 0; w < 4; ++w) {
        const int src = ((quad & 1) * 2 + (w >> 1)) * 16 + ln;
        const int loA = __shfl((int)pkA[2 * kt][w & 1], src, 64);
        const int hiA = __shfl((int)pkA[2 * kt + 1][w & 1], src, 64);
        pawA[kt][w] = (unsigned)((quad & 2) ? hiA : loA);
        const int loB = __shfl((int)pkB[2 * kt][w & 1], src, 64);
        const int hiB = __shfl((int)pkB[2 * kt + 1][w & 1], src, 64);
        pawB[kt][w] = (unsigned)((quad & 2) ? hiB : loB);
      }

    __syncthreads();   // V(j) staged (vmcnt drained) before PV reads

    #pragma unroll
    for (int kt = 0; kt < 2; ++kt) {
      union { unsigned u[4]; bf16x8 b; } paA, paB;
      #pragma unroll
      for (int w = 0; w < 4; ++w) { paA.u[w] = pawA[kt][w]; paB.u[w] = pawB[kt][w]; }
      #pragma unroll
      for (int dt = 0; dt < 8; ++dt) {
        const int row = dt * 16 + ln;
        const int sw = (row & 7) << 4;
        bf16x8 vb = *(const bf16x8*)&Vs[row * 64 +
                                        (((kt * 64 + quad * 16) ^ sw) >> 1)];
        ofA[dt] = mfma16(vb, paA.b, ofA[dt]);
        ofB[dt] = mfma16(vb, paB.b, ofB[dt]);
      }
    }

    __syncthreads();   // all waves done reading Vs -> safe to overwrite

    if (j < 31) {
      #pragma unroll
      for (int i = 0; i < 4; ++i)
        gload_lds16(vg + (size_t)vrow[i] * 2048 + (j + 1) * 64 + (vscol[i] >> 1),
                    &Vs[(wv * 4 + i) * 512 + lane * 8]);
    }
    cur ^= 1;
  }

  const float invA = 1.0f / lA, invB = 1.0f / lB;
  #pragma unroll
  for (int dt = 0; dt < 8; ++dt) {
    u16x4 oa, ob;
    #pragma unroll
    for (int r = 0; r < 4; ++r) {
      oa[r] = f2bf(ofA[dt][r] * invA);
      ob[r] = f2bf(ofB[dt][r] * invB);
    }
    *(u16x4*)&O[((size_t)(b * 2048 + m0 + wv * 16 + ln)) * 2048 +
                h * 128 + dt * 16 + quad * 4] = oa;
    *(u16x4*)&O[((size_t)(b * 2048 + m0 + 64 + wv * 16 + ln)) * 2048 +
                h * 128 + dt * 16 + quad * 4] = ob;
  }
}

// ---------------------------------------------------------------------------
// Launch. Workspace layout (MiB offsets), phase-aliased, peak 104 MiB.
// ---------------------------------------------------------------------------
extern "C" void kernel_launch(void* const* d_in, const int* in_sizes, int n_in,
                              void* d_out, int out_size, void* d_ws, size_t ws_size,
                              hipStream_t stream) {
  const float* query     = (const float*)d_in[0];
  const float* key_value = (const float*)d_in[1];
  const float* g_q       = (const float*)d_in[2];
  const float* g_kv      = (const float*)d_in[3];
  const float* g_ffn     = (const float*)d_in[4];
  const float* w_qc      = (const float*)d_in[5];
  const float* w_kc      = (const float*)d_in[6];
  const float* w_qr      = (const float*)d_in[7];
  const float* w_kr      = (const float*)d_in[8];
  const float* w_v       = (const float*)d_in[9];
  const float* w_o       = (const float*)d_in[10];
  const float* w_gate    = (const float*)d_in[11];
  const float* w_up      = (const float*)d_in[12];
  const float* w_down    = (const float*)d_in[13];

  char* ws = (char*)d_ws;
  const size_t MiB = 1048576;
  u16*   qn   = (u16*)(ws + 0 * MiB);
  u16*   kvn  = (u16*)(ws + 16 * MiB);
  u16*   Qb   = (u16*)(ws + 32 * MiB);
  u16*   Kb   = (u16*)(ws + 56 * MiB);
  u16*   Vb   = (u16*)(ws + 80 * MiB);
  u16*   wt   = (u16*)(ws + 96 * MiB);   // 8 MiB slab (proj weights)
  u16*   VT   = (u16*)(ws + 0 * MiB);    // over qn (dead)
  u16*   attn = (u16*)(ws + 16 * MiB);   // over kvn (dead)
  float* x    = (float*)(ws + 64 * MiB); // over Kb-tail+Vb (dead)
  u16*   xn   = (u16*)(ws + 0 * MiB);    // over VT (dead)
  u16*   ghalf= (u16*)(ws + 16 * MiB);   // over attn+Qb-head (dead), 32 MiB
  u16*   wtf  = (u16*)(ws + 48 * MiB);   // over Qb-tail+Kb-head (dead), 16 MiB

  const dim3 blk(256);

  // input norms
  rmsnorm_k<<<4096, blk, 0, stream>>>(query, g_q, qn);
  rmsnorm_k<<<4096, blk, 0, stream>>>(key_value, g_kv, kvn);

  // Q projections (qn dead after these)
  conv_t<<<dim3(32, 32), blk, 0, stream>>>(w_qc, wt, 2048, 2048, 2048);
  gemm_bt<1><<<dim3(16, 32), blk, 0, stream>>>(qn, wt, 2048, 2048, Qb, nullptr);
  conv_t<<<dim3(16, 32), blk, 0, stream>>>(w_qr, wt, 2048, 1024, 1024);
  gemm_bt<2><<<dim3(8, 32), blk, 0, stream>>>(qn, wt, 1024, 2048, Qb, nullptr);
  // K projections
  conv_t<<<dim3(32, 32), blk, 0, stream>>>(w_kc, wt, 2048, 2048, 2048);
  gemm_bt<3><<<dim3(16, 32), blk, 0, stream>>>(kvn, wt, 2048, 2048, Kb, nullptr);
  conv_t<<<dim3(16, 32), blk, 0, stream>>>(w_kr, wt, 2048, 1024, 1024);
  gemm_bt<4><<<dim3(8, 32), blk, 0, stream>>>(kvn, wt, 1024, 2048, Kb, nullptr);
  // V projection (kvn dead after)
  conv_t<<<dim3(32, 32), blk, 0, stream>>>(w_v, wt, 2048, 2048, 2048);
  gemm_bt<5><<<dim3(16, 32), blk, 0, stream>>>(kvn, wt, 2048, 2048, Vb, nullptr);

  // RoPE tails
  rope_k<<<8192, blk, 0, stream>>>(Qb);
  rope_k<<<8192, blk, 0, stream>>>(Kb);

  // V -> V^T per head (Vb -> VT; VT aliases dead qn)
  transpose_bf16<<<dim3(2, 32, 32), blk, 0, stream>>>(Vb, VT, 2048, 128);

  // flash attention -> attn (aliases dead kvn)
  flash_k<<<dim3(16, 16, 2), blk, 0, stream>>>(Qb, Kb, VT, attn);

  // out projection + residual -> x fp32 (aliases dead Kb-tail/Vb)
  conv_t<<<dim3(32, 32), blk, 0, stream>>>(w_o, wt, 2048, 2048, 2048);
  gemm_bt<6><<<dim3(16, 32), blk, 0, stream>>>(attn, wt, 2048, 2048, x, query);

  // FFN: rmsnorm then two N=4096 halves with split-K accumulation into d_out
  rmsnorm_k<<<4096, blk, 0, stream>>>(x, g_ffn, xn);
  for (int h = 0; h < 2; ++h) {
    const int n0 = h * 4096;
    conv_t<<<dim3(64, 32), blk, 0, stream>>>(w_gate + n0, wtf, 2048, 4096, 8192);
    gemm256<0><<<dim3(16, 16), dim3(512), 0, stream>>>(xn, wtf, 4096, 2048, ghalf, nullptr);
    conv_t<<<dim3(64, 32), blk, 0, stream>>>(w_up + n0, wtf, 2048, 4096, 8192);
    gemm256<7><<<dim3(16, 16), dim3(512), 0, stream>>>(xn, wtf, 4096, 2048, ghalf, ghalf);
    conv_t<<<dim3(32, 64), blk, 0, stream>>>(w_down + (size_t)n0 * 2048, wtf,
                                             4096, 2048, 2048);
    gemm_bt<6><<<dim3(16, 32), blk, 0, stream>>>(ghalf, wtf, 2048, 4096,
                                                 (float*)d_out,
                                                 h == 0 ? (const void*)x
                                                        : (const void*)d_out);
  }
}